// Round 2
// baseline (3314.556 us; speedup 1.0000x reference)
//
#include <hip/hip_runtime.h>

// GCN 2-layer: out = Ahat( relu( Ahat(x) W1 + b1 ) W2 ) + b2, Ahat = D^-1/2 (A+I) D^-1/2.
// Key identity: Ahat(x W1) = (Ahat x) W1 -> aggregate in 64-dim space both times.
// dims: in=64, hid=128, out=64; N=100000, E=1.6M.
// ws usage kept ~26MB (round-1 failure: 98MB layout overran ws_size and corrupted
// the harness's pristine input copies -> post-timing divergence).

#define DIM 64

__device__ __forceinline__ void atomAddF(float* p, float v) {
    unsafeAtomicAdd(p, v);   // guaranteed global_atomic_add_f32 on gfx90a+
}

__global__ __launch_bounds__(256) void k_init_deg(float* deg, int n) {
    int i = blockIdx.x * 256 + threadIdx.x;
    if (i < n) deg[i] = 1.0f;  // self-loop
}

__global__ __launch_bounds__(256) void k_count_deg(const int* __restrict__ ei, float* deg, int E) {
    int e = blockIdx.x * 256 + threadIdx.x;
    if (e < E) atomAddF(&deg[ei[E + e]], 1.0f);  // dst row
}

__global__ __launch_bounds__(256) void k_rsqrt(float* deg, int n) {
    int i = blockIdx.x * 256 + threadIdx.x;
    if (i < n) deg[i] = rsqrtf(deg[i]);
}

// out[i] = src[i]*dinv[i]^2 (+ bias). 16 lanes per row (float4 each).
template<bool BIAS>
__global__ __launch_bounds__(256) void k_self(const float* __restrict__ src,
                                              const float* __restrict__ dinv,
                                              const float* __restrict__ b,
                                              float* __restrict__ out, int n) {
    int g = blockIdx.x * 256 + threadIdx.x;
    int i = g >> 4, c = g & 15;
    if (i >= n) return;
    float di = dinv[i];
    float s = di * di;
    float4 v = *(const float4*)&src[(long)i * DIM + c * 4];
    float4 r = make_float4(v.x * s, v.y * s, v.z * s, v.w * s);
    if (BIAS) {
        float4 bv = *(const float4*)&b[c * 4];
        r.x += bv.x; r.y += bv.y; r.z += bv.z; r.w += bv.w;
    }
    *(float4*)&out[(long)i * DIM + c * 4] = r;
}

// per edge: out[dst] += h[src] * dinv[src]*dinv[dst].  16 lanes/edge, float4 gather.
__global__ __launch_bounds__(256) void k_edge_agg(const int* __restrict__ ei,
                                                  const float* __restrict__ dinv,
                                                  const float* __restrict__ h,
                                                  float* __restrict__ out, int E) {
    int t = threadIdx.x;
    int e = blockIdx.x * 16 + (t >> 4);
    if (e >= E) return;
    int lane = t & 15;
    int s = ei[e];
    int d = ei[E + e];
    float norm = dinv[s] * dinv[d];
    float4 hv = *(const float4*)&h[(long)s * DIM + lane * 4];
    float* o = &out[(long)d * DIM + lane * 4];
    atomAddF(o + 0, hv.x * norm);
    atomAddF(o + 1, hv.y * norm);
    atomAddF(o + 2, hv.z * norm);
    atomAddF(o + 3, hv.w * norm);
}

// T = relu(G @ W1 + b1) @ W2, in-place capable (T==G): 32-row tile per block,
// h-tile (32x128) lives only in LDS. 256 threads.
__global__ __launch_bounds__(256) void k_fused_mlp(const float* __restrict__ G,  // [N,64]
                                                   const float* __restrict__ W1, // [64,128]
                                                   const float* __restrict__ b1, // [128]
                                                   const float* __restrict__ W2, // [128,64]
                                                   float* __restrict__ T,        // [N,64]
                                                   int M) {
    __shared__ float As[32][68];    // agg tile, padded
    __shared__ float Ws[64 * 128];  // W1 flat, then reused as W2 [128][64] flat
    __shared__ float Hs[32][132];   // relu(h) tile, padded
    const int tid = threadIdx.x;
    const int row0 = blockIdx.x * 32;
    const int ty = tid >> 4;        // 0..15 -> 2 rows each
    const int tx = tid & 15;        // 0..15

    // stage A tile (32x64): 512 float4, 2/thread
    #pragma unroll
    for (int l = 0; l < 2; ++l) {
        int idx = l * 256 + tid;          // 0..511
        int r = idx >> 4, cv = idx & 15;
        int gr = row0 + r;
        float4 v = make_float4(0.f, 0.f, 0.f, 0.f);
        if (gr < M) v = *(const float4*)&G[(long)gr * DIM + cv * 4];
        *(float4*)&As[r][cv * 4] = v;
    }
    // stage W1 (8192 floats flat): 8 float4/thread
    #pragma unroll
    for (int l = 0; l < 8; ++l) {
        int idx = (l * 256 + tid) * 4;
        *(float4*)&Ws[idx] = *(const float4*)&W1[idx];
    }
    __syncthreads();

    // stage 1: h(32x128) = As @ W1; rows ty*2+{0,1}, cols tx*8..+7
    float acc[2][8] = {};
    #pragma unroll
    for (int k = 0; k < 64; ++k) {
        float a0 = As[ty * 2 + 0][k];
        float a1 = As[ty * 2 + 1][k];
        const float* wr = &Ws[k * 128 + tx * 8];
        float4 wA = *(const float4*)wr;
        float4 wB = *(const float4*)(wr + 4);
        float wv[8] = {wA.x, wA.y, wA.z, wA.w, wB.x, wB.y, wB.z, wB.w};
        #pragma unroll
        for (int j = 0; j < 8; ++j) {
            acc[0][j] += a0 * wv[j];
            acc[1][j] += a1 * wv[j];
        }
    }
    float bv[8];
    *(float4*)&bv[0] = *(const float4*)&b1[tx * 8];
    *(float4*)&bv[4] = *(const float4*)&b1[tx * 8 + 4];
    #pragma unroll
    for (int i = 0; i < 2; ++i)
        #pragma unroll
        for (int j = 0; j < 8; ++j)
            Hs[ty * 2 + i][tx * 8 + j] = fmaxf(acc[i][j] + bv[j], 0.f);
    __syncthreads();   // Hs complete; all W1 reads done

    // stage W2 (128x64 flat = 8192 floats) over W1's LDS
    #pragma unroll
    for (int l = 0; l < 8; ++l) {
        int idx = (l * 256 + tid) * 4;
        *(float4*)&Ws[idx] = *(const float4*)&W2[idx];
    }
    __syncthreads();

    // stage 2: t(32x64) = Hs @ W2; rows ty*2+{0,1}, cols tx*4..+3
    float acc2[2][4] = {};
    #pragma unroll
    for (int k = 0; k < 128; ++k) {
        float a0 = Hs[ty * 2 + 0][k];
        float a1 = Hs[ty * 2 + 1][k];
        float4 w = *(const float4*)&Ws[k * 64 + tx * 4];
        acc2[0][0] += a0 * w.x; acc2[0][1] += a0 * w.y; acc2[0][2] += a0 * w.z; acc2[0][3] += a0 * w.w;
        acc2[1][0] += a1 * w.x; acc2[1][1] += a1 * w.y; acc2[1][2] += a1 * w.z; acc2[1][3] += a1 * w.w;
    }
    #pragma unroll
    for (int i = 0; i < 2; ++i) {
        int gr = row0 + ty * 2 + i;
        if (gr < M)
            *(float4*)&T[(long)gr * DIM + tx * 4] =
                make_float4(acc2[i][0], acc2[i][1], acc2[i][2], acc2[i][3]);
    }
}

extern "C" void kernel_launch(void* const* d_in, const int* in_sizes, int n_in,
                              void* d_out, int out_size, void* d_ws, size_t ws_size,
                              hipStream_t stream) {
    const float* x  = (const float*)d_in[0];
    const int*   ei = (const int*)d_in[1];   // [2,E] int32
    const float* W1 = (const float*)d_in[2];
    const float* b1 = (const float*)d_in[3];
    const float* W2 = (const float*)d_in[4];
    const float* b2 = (const float*)d_in[5];
    float* out = (float*)d_out;

    const int N = in_sizes[0] / DIM;   // 100000
    const int E = in_sizes[1] / 2;     // 1600000

    // ws: [dinv: N floats][pad to 512KB][buf: N*64 floats]  total ~26.1MB
    char* ws = (char*)d_ws;
    float* dinv = (float*)ws;
    float* buf  = (float*)(ws + 512 * 1024);

    int gn = (N + 255) / 256;
    int ge = (E + 255) / 256;
    int gl = ((long)N * 16 + 255) / 256;     // 16 lanes/row kernels
    int gedge = (E + 15) / 16;               // 16 edges/block

    // dinv = rsqrt(1 + indeg)
    k_init_deg<<<gn, 256, 0, stream>>>(dinv, N);
    k_count_deg<<<ge, 256, 0, stream>>>(ei, dinv, E);
    k_rsqrt<<<gn, 256, 0, stream>>>(dinv, N);

    // buf = Ahat x   (self term then edge scatter)
    k_self<false><<<gl, 256, 0, stream>>>(x, dinv, nullptr, buf, N);
    k_edge_agg<<<gedge, 256, 0, stream>>>(ei, dinv, x, buf, E);

    // buf = relu(buf @ W1 + b1) @ W2   (in-place, row-tile-local)
    k_fused_mlp<<<(N + 31) / 32, 256, 0, stream>>>(buf, W1, b1, W2, buf, N);

    // out = Ahat buf + b2
    k_self<true><<<gl, 256, 0, stream>>>(buf, dinv, b2, out, N);
    k_edge_agg<<<gedge, 256, 0, stream>>>(ei, dinv, buf, out, E);
}

// Round 3
// 855.807 us; speedup vs baseline: 3.8730x; 3.8730x over previous
//
#include <hip/hip_runtime.h>

// GCN 2-layer: out = Ahat( relu( Ahat(x) W1 + b1 ) W2 ) + b2, Ahat = D^-1/2 (A+I) D^-1/2.
// Ahat(x W1) = (Ahat x) W1 -> aggregate in 64-dim space both times.
// N=100000, E=1.6M, dims 64->128->64.
//
// R2 post-mortem: atomic scatter was the bottleneck (102M f32 atomics, WRITE_SIZE
// 1.6GB = 64B/atomic through TCC, VALUBusy 1%). R3: build CSR once, aggregate by
// gather (no atomics). Fallback to the R2 atomic path if ws_size < CSR layout.

#define DIM 64

__device__ __forceinline__ void atomAddF(float* p, float v) {
    unsafeAtomicAdd(p, v);
}

// ---------------- CSR build ----------------
__global__ __launch_bounds__(256) void k_zero_i(int* p, int n) {
    int i = blockIdx.x * 256 + threadIdx.x;
    if (i < n) p[i] = 0;
}
__global__ __launch_bounds__(256) void k_hist(const int* __restrict__ ei, int* counts, int E) {
    int e = blockIdx.x * 256 + threadIdx.x;
    if (e < E) atomicAdd(&counts[ei[E + e]], 1);   // in-degree of dst
}
// per-block exclusive scan of counts -> row_ptr (block-local), block totals -> partials
__global__ __launch_bounds__(256) void k_scan1(const int* __restrict__ counts,
                                               int* __restrict__ row_ptr,
                                               int* __restrict__ partials, int n) {
    __shared__ int s[256];
    int tid = threadIdx.x;
    int i = blockIdx.x * 256 + tid;
    int v = (i < n) ? counts[i] : 0;
    s[tid] = v; __syncthreads();
    #pragma unroll
    for (int off = 1; off < 256; off <<= 1) {
        int t = (tid >= off) ? s[tid - off] : 0;
        __syncthreads();
        s[tid] += t;
        __syncthreads();
    }
    if (i < n) row_ptr[i] = s[tid] - v;            // exclusive
    if (tid == 255) partials[blockIdx.x] = s[255]; // inclusive total
}
// single-block exclusive scan of partials (nb <= 1024)
__global__ __launch_bounds__(1024) void k_scan2(int* partials, int nb) {
    __shared__ int s[1024];
    int tid = threadIdx.x;
    int v = (tid < nb) ? partials[tid] : 0;
    s[tid] = v; __syncthreads();
    for (int off = 1; off < 1024; off <<= 1) {
        int t = (tid >= off) ? s[tid - off] : 0;
        __syncthreads();
        s[tid] += t;
        __syncthreads();
    }
    if (tid < nb) partials[tid] = s[tid] - v;
}
__global__ __launch_bounds__(256) void k_scan3(int* __restrict__ row_ptr,
                                               const int* __restrict__ partials, int n, int E) {
    int i = blockIdx.x * 256 + threadIdx.x;
    if (i < n) row_ptr[i] += partials[blockIdx.x];
    if (i == 0) row_ptr[n] = E;
}
__global__ __launch_bounds__(256) void k_dinv_copy(const int* __restrict__ row_ptr,
                                                   float* __restrict__ dinv,
                                                   int* __restrict__ cursor, int n) {
    int i = blockIdx.x * 256 + threadIdx.x;
    if (i < n) {
        int r0 = row_ptr[i];
        dinv[i] = rsqrtf(1.0f + (float)(row_ptr[i + 1] - r0));  // +1 self-loop
        cursor[i] = r0;
    }
}
__global__ __launch_bounds__(256) void k_scatter(const int* __restrict__ ei,
                                                 int* __restrict__ cursor,
                                                 int* __restrict__ col, int E) {
    int e = blockIdx.x * 256 + threadIdx.x;
    if (e < E) {
        int d = ei[E + e];
        int pos = atomicAdd(&cursor[d], 1);
        col[pos] = ei[e];   // src
    }
}

// ---------------- CSR aggregation (atomic-free) ----------------
// out[d] = dinv[d] * ( dinv[d]*h[d] + sum_{s in N(d)} dinv[s]*h[s] ) [+ b]
// 16 lanes per node (float4 each), 16 nodes per block.
template<bool BIAS>
__global__ __launch_bounds__(256) void k_agg_csr(const int* __restrict__ row_ptr,
                                                 const int* __restrict__ col,
                                                 const float* __restrict__ dinv,
                                                 const float* __restrict__ h,
                                                 const float* __restrict__ b,
                                                 float* __restrict__ out, int n) {
    int g = blockIdx.x * 16 + (threadIdx.x >> 4);
    if (g >= n) return;
    int lane = threadIdx.x & 15;
    const float4* h4 = (const float4*)h;
    float di = dinv[g];
    float4 hv = h4[(long)g * 16 + lane];
    float4 acc = make_float4(hv.x * di, hv.y * di, hv.z * di, hv.w * di);  // self term
    int e1 = row_ptr[g + 1];
    for (int e = row_ptr[g]; e < e1; ++e) {
        int s = col[e];
        float ds = dinv[s];
        float4 v = h4[(long)s * 16 + lane];
        acc.x += ds * v.x; acc.y += ds * v.y; acc.z += ds * v.z; acc.w += ds * v.w;
    }
    acc.x *= di; acc.y *= di; acc.z *= di; acc.w *= di;
    if (BIAS) {
        float4 bv = ((const float4*)b)[lane];
        acc.x += bv.x; acc.y += bv.y; acc.z += bv.z; acc.w += bv.w;
    }
    ((float4*)out)[(long)g * 16 + lane] = acc;
}

// ---------------- fused MLP: T = relu(G @ W1 + b1) @ W2 ----------------
__global__ __launch_bounds__(256) void k_fused_mlp(const float* __restrict__ G,  // [N,64]
                                                   const float* __restrict__ W1, // [64,128]
                                                   const float* __restrict__ b1, // [128]
                                                   const float* __restrict__ W2, // [128,64]
                                                   float* __restrict__ T,        // [N,64]
                                                   int M) {
    __shared__ float As[32][68];
    __shared__ float Ws[64 * 128];
    __shared__ float Hs[32][132];
    const int tid = threadIdx.x;
    const int row0 = blockIdx.x * 32;
    const int ty = tid >> 4;
    const int tx = tid & 15;

    #pragma unroll
    for (int l = 0; l < 2; ++l) {
        int idx = l * 256 + tid;
        int r = idx >> 4, cv = idx & 15;
        int gr = row0 + r;
        float4 v = make_float4(0.f, 0.f, 0.f, 0.f);
        if (gr < M) v = *(const float4*)&G[(long)gr * DIM + cv * 4];
        *(float4*)&As[r][cv * 4] = v;
    }
    #pragma unroll
    for (int l = 0; l < 8; ++l) {
        int idx = (l * 256 + tid) * 4;
        *(float4*)&Ws[idx] = *(const float4*)&W1[idx];
    }
    __syncthreads();

    float acc[2][8] = {};
    #pragma unroll
    for (int k = 0; k < 64; ++k) {
        float a0 = As[ty * 2 + 0][k];
        float a1 = As[ty * 2 + 1][k];
        const float* wr = &Ws[k * 128 + tx * 8];
        float4 wA = *(const float4*)wr;
        float4 wB = *(const float4*)(wr + 4);
        float wv[8] = {wA.x, wA.y, wA.z, wA.w, wB.x, wB.y, wB.z, wB.w};
        #pragma unroll
        for (int j = 0; j < 8; ++j) { acc[0][j] += a0 * wv[j]; acc[1][j] += a1 * wv[j]; }
    }
    float bv[8];
    *(float4*)&bv[0] = *(const float4*)&b1[tx * 8];
    *(float4*)&bv[4] = *(const float4*)&b1[tx * 8 + 4];
    #pragma unroll
    for (int i = 0; i < 2; ++i)
        #pragma unroll
        for (int j = 0; j < 8; ++j)
            Hs[ty * 2 + i][tx * 8 + j] = fmaxf(acc[i][j] + bv[j], 0.f);
    __syncthreads();

    #pragma unroll
    for (int l = 0; l < 8; ++l) {
        int idx = (l * 256 + tid) * 4;
        *(float4*)&Ws[idx] = *(const float4*)&W2[idx];
    }
    __syncthreads();

    float acc2[2][4] = {};
    #pragma unroll
    for (int k = 0; k < 128; ++k) {
        float a0 = Hs[ty * 2 + 0][k];
        float a1 = Hs[ty * 2 + 1][k];
        float4 w = *(const float4*)&Ws[k * 64 + tx * 4];
        acc2[0][0] += a0 * w.x; acc2[0][1] += a0 * w.y; acc2[0][2] += a0 * w.z; acc2[0][3] += a0 * w.w;
        acc2[1][0] += a1 * w.x; acc2[1][1] += a1 * w.y; acc2[1][2] += a1 * w.z; acc2[1][3] += a1 * w.w;
    }
    #pragma unroll
    for (int i = 0; i < 2; ++i) {
        int gr = row0 + ty * 2 + i;
        if (gr < M)
            *(float4*)&T[(long)gr * DIM + tx * 4] =
                make_float4(acc2[i][0], acc2[i][1], acc2[i][2], acc2[i][3]);
    }
}

// ---------------- R2 fallback path (atomic scatter) ----------------
__global__ __launch_bounds__(256) void k_init_deg(float* deg, int n) {
    int i = blockIdx.x * 256 + threadIdx.x;
    if (i < n) deg[i] = 1.0f;
}
__global__ __launch_bounds__(256) void k_count_deg(const int* __restrict__ ei, float* deg, int E) {
    int e = blockIdx.x * 256 + threadIdx.x;
    if (e < E) atomAddF(&deg[ei[E + e]], 1.0f);
}
__global__ __launch_bounds__(256) void k_rsqrt(float* deg, int n) {
    int i = blockIdx.x * 256 + threadIdx.x;
    if (i < n) deg[i] = rsqrtf(deg[i]);
}
template<bool BIAS>
__global__ __launch_bounds__(256) void k_self(const float* __restrict__ src,
                                              const float* __restrict__ dinv,
                                              const float* __restrict__ b,
                                              float* __restrict__ out, int n) {
    int g = blockIdx.x * 256 + threadIdx.x;
    int i = g >> 4, c = g & 15;
    if (i >= n) return;
    float di = dinv[i];
    float s = di * di;
    float4 v = *(const float4*)&src[(long)i * DIM + c * 4];
    float4 r = make_float4(v.x * s, v.y * s, v.z * s, v.w * s);
    if (BIAS) {
        float4 bv = *(const float4*)&b[c * 4];
        r.x += bv.x; r.y += bv.y; r.z += bv.z; r.w += bv.w;
    }
    *(float4*)&out[(long)i * DIM + c * 4] = r;
}
__global__ __launch_bounds__(256) void k_edge_agg(const int* __restrict__ ei,
                                                  const float* __restrict__ dinv,
                                                  const float* __restrict__ h,
                                                  float* __restrict__ out, int E) {
    int t = threadIdx.x;
    int e = blockIdx.x * 16 + (t >> 4);
    if (e >= E) return;
    int lane = t & 15;
    int s = ei[e];
    int d = ei[E + e];
    float norm = dinv[s] * dinv[d];
    float4 hv = *(const float4*)&h[(long)s * DIM + lane * 4];
    float* o = &out[(long)d * DIM + lane * 4];
    atomAddF(o + 0, hv.x * norm);
    atomAddF(o + 1, hv.y * norm);
    atomAddF(o + 2, hv.z * norm);
    atomAddF(o + 3, hv.w * norm);
}

extern "C" void kernel_launch(void* const* d_in, const int* in_sizes, int n_in,
                              void* d_out, int out_size, void* d_ws, size_t ws_size,
                              hipStream_t stream) {
    const float* x  = (const float*)d_in[0];
    const int*   ei = (const int*)d_in[1];   // [2,E] int32
    const float* W1 = (const float*)d_in[2];
    const float* b1 = (const float*)d_in[3];
    const float* W2 = (const float*)d_in[4];
    const float* b2 = (const float*)d_in[5];
    float* out = (float*)d_out;

    const int N = in_sizes[0] / DIM;   // 100000
    const int E = in_sizes[1] / 2;     // 1600000

    const int gn  = (N + 255) / 256;       // 391
    const int ge  = (E + 255) / 256;
    const int gagg = (N + 15) / 16;
    const int gmlp = (N + 31) / 32;

    // CSR layout in ws (256B-aligned bump)
    size_t off = 0;
    auto bump = [&](size_t bytes) { size_t o = off; off = (off + bytes + 255) & ~(size_t)255; return o; };
    size_t o_dinv    = bump((size_t)N * 4);
    size_t o_rowptr  = bump((size_t)(N + 1) * 4);
    size_t o_cursor  = bump((size_t)N * 4);        // doubles as counts
    size_t o_part    = bump(4096 * 4);
    size_t o_col     = bump((size_t)E * 4);
    size_t o_buf     = bump((size_t)N * DIM * 4);
    size_t need_csr  = off;

    char* ws = (char*)d_ws;

    if (ws_size >= need_csr) {
        // -------- CSR path --------
        float* dinv   = (float*)(ws + o_dinv);
        int*   rowptr = (int*)(ws + o_rowptr);
        int*   cursor = (int*)(ws + o_cursor);
        int*   part   = (int*)(ws + o_part);
        int*   col    = (int*)(ws + o_col);
        float* buf    = (float*)(ws + o_buf);

        k_zero_i<<<gn, 256, 0, stream>>>(cursor, N);                       // counts
        k_hist<<<ge, 256, 0, stream>>>(ei, cursor, E);
        k_scan1<<<gn, 256, 0, stream>>>(cursor, rowptr, part, N);
        k_scan2<<<1, 1024, 0, stream>>>(part, gn);
        k_scan3<<<gn, 256, 0, stream>>>(rowptr, part, N, E);
        k_dinv_copy<<<gn, 256, 0, stream>>>(rowptr, dinv, cursor, N);
        k_scatter<<<ge, 256, 0, stream>>>(ei, cursor, col, E);

        // d_out = Ahat x
        k_agg_csr<false><<<gagg, 256, 0, stream>>>(rowptr, col, dinv, x, nullptr, out, N);
        // buf = relu(d_out @ W1 + b1) @ W2
        k_fused_mlp<<<gmlp, 256, 0, stream>>>(out, W1, b1, W2, buf, N);
        // d_out = Ahat buf + b2
        k_agg_csr<true><<<gagg, 256, 0, stream>>>(rowptr, col, dinv, buf, b2, out, N);
    } else {
        // -------- R2 fallback (atomic scatter) --------
        float* dinv = (float*)ws;
        float* buf  = (float*)(ws + 512 * 1024);
        int gl = ((long)N * 16 + 255) / 256;
        int gedge = (E + 15) / 16;

        k_init_deg<<<gn, 256, 0, stream>>>(dinv, N);
        k_count_deg<<<ge, 256, 0, stream>>>(ei, dinv, E);
        k_rsqrt<<<gn, 256, 0, stream>>>(dinv, N);

        k_self<false><<<gl, 256, 0, stream>>>(x, dinv, nullptr, buf, N);
        k_edge_agg<<<gedge, 256, 0, stream>>>(ei, dinv, x, buf, E);
        k_fused_mlp<<<gmlp, 256, 0, stream>>>(buf, W1, b1, W2, buf, N);
        k_self<true><<<gl, 256, 0, stream>>>(buf, dinv, b2, out, N);
        k_edge_agg<<<gedge, 256, 0, stream>>>(ei, dinv, buf, out, E);
    }
}

// Round 4
// 503.614 us; speedup vs baseline: 6.5815x; 1.6993x over previous
//
#include <hip/hip_runtime.h>

// GCN 2-layer: out = Ahat( relu( Ahat(x) W1 + b1 ) W2 ) + b2, Ahat = D^-1/2 (A+I) D^-1/2.
// Ahat(x W1) = (Ahat x) W1 -> aggregate in 64-dim space both times.
// N=100000, E=1.6M, dims 64->128->64.
//
// R3 post-mortem: k_fused_mlp spilled (VGPR=256 cap, WRITE_SIZE 563MB of scratch
// traffic, 433us). Cause: full #pragma unroll on k=64/128 loops. R4: bounded
// k+=4 steps, float4 accumulators, no scalar temp arrays.

#define DIM 64

__device__ __forceinline__ void atomAddF(float* p, float v) {
    unsafeAtomicAdd(p, v);
}

// ---------------- CSR build ----------------
__global__ __launch_bounds__(256) void k_zero_i(int* p, int n) {
    int i = blockIdx.x * 256 + threadIdx.x;
    if (i < n) p[i] = 0;
}
__global__ __launch_bounds__(256) void k_hist(const int* __restrict__ ei, int* counts, int E) {
    int e = blockIdx.x * 256 + threadIdx.x;
    if (e < E) atomicAdd(&counts[ei[E + e]], 1);   // in-degree of dst
}
__global__ __launch_bounds__(256) void k_scan1(const int* __restrict__ counts,
                                               int* __restrict__ row_ptr,
                                               int* __restrict__ partials, int n) {
    __shared__ int s[256];
    int tid = threadIdx.x;
    int i = blockIdx.x * 256 + tid;
    int v = (i < n) ? counts[i] : 0;
    s[tid] = v; __syncthreads();
    for (int off = 1; off < 256; off <<= 1) {
        int t = (tid >= off) ? s[tid - off] : 0;
        __syncthreads();
        s[tid] += t;
        __syncthreads();
    }
    if (i < n) row_ptr[i] = s[tid] - v;            // exclusive
    if (tid == 255) partials[blockIdx.x] = s[255]; // inclusive total
}
__global__ __launch_bounds__(1024) void k_scan2(int* partials, int nb) {
    __shared__ int s[1024];
    int tid = threadIdx.x;
    int v = (tid < nb) ? partials[tid] : 0;
    s[tid] = v; __syncthreads();
    for (int off = 1; off < 1024; off <<= 1) {
        int t = (tid >= off) ? s[tid - off] : 0;
        __syncthreads();
        s[tid] += t;
        __syncthreads();
    }
    if (tid < nb) partials[tid] = s[tid] - v;
}
__global__ __launch_bounds__(256) void k_scan3(int* __restrict__ row_ptr,
                                               const int* __restrict__ partials, int n, int E) {
    int i = blockIdx.x * 256 + threadIdx.x;
    if (i < n) row_ptr[i] += partials[blockIdx.x];
    if (i == 0) row_ptr[n] = E;
}
__global__ __launch_bounds__(256) void k_dinv_copy(const int* __restrict__ row_ptr,
                                                   float* __restrict__ dinv,
                                                   int* __restrict__ cursor, int n) {
    int i = blockIdx.x * 256 + threadIdx.x;
    if (i < n) {
        int r0 = row_ptr[i];
        dinv[i] = rsqrtf(1.0f + (float)(row_ptr[i + 1] - r0));  // +1 self-loop
        cursor[i] = r0;
    }
}
__global__ __launch_bounds__(256) void k_scatter(const int* __restrict__ ei,
                                                 int* __restrict__ cursor,
                                                 int* __restrict__ col, int E) {
    int e = blockIdx.x * 256 + threadIdx.x;
    if (e < E) {
        int d = ei[E + e];
        int pos = atomicAdd(&cursor[d], 1);
        col[pos] = ei[e];   // src
    }
}

// ---------------- CSR aggregation (atomic-free) ----------------
// out[d] = dinv[d] * ( dinv[d]*h[d] + sum_{s in N(d)} dinv[s]*h[s] ) [+ b]
template<bool BIAS>
__global__ __launch_bounds__(256) void k_agg_csr(const int* __restrict__ row_ptr,
                                                 const int* __restrict__ col,
                                                 const float* __restrict__ dinv,
                                                 const float* __restrict__ h,
                                                 const float* __restrict__ b,
                                                 float* __restrict__ out, int n) {
    int g = blockIdx.x * 16 + (threadIdx.x >> 4);
    if (g >= n) return;
    int lane = threadIdx.x & 15;
    const float4* h4 = (const float4*)h;
    float di = dinv[g];
    float4 hv = h4[(long)g * 16 + lane];
    float4 acc = make_float4(hv.x * di, hv.y * di, hv.z * di, hv.w * di);  // self term
    int e1 = row_ptr[g + 1];
    for (int e = row_ptr[g]; e < e1; ++e) {
        int s = col[e];
        float ds = dinv[s];
        float4 v = h4[(long)s * 16 + lane];
        acc.x += ds * v.x; acc.y += ds * v.y; acc.z += ds * v.z; acc.w += ds * v.w;
    }
    acc.x *= di; acc.y *= di; acc.z *= di; acc.w *= di;
    if (BIAS) {
        float4 bv = ((const float4*)b)[lane];
        acc.x += bv.x; acc.y += bv.y; acc.z += bv.z; acc.w += bv.w;
    }
    ((float4*)out)[(long)g * 16 + lane] = acc;
}

// ---------------- fused MLP v2: T = relu(G @ W1 + b1) @ W2 ----------------
// 32-row tile / block of 256. Bounded k-unroll (k+=4), float4 accs, no spills.
__global__ __launch_bounds__(256) void k_fused_mlp(const float* __restrict__ G,  // [N,64]
                                                   const float* __restrict__ W1, // [64,128]
                                                   const float* __restrict__ b1, // [128]
                                                   const float* __restrict__ W2, // [128,64]
                                                   float* __restrict__ T,        // [N,64]
                                                   int M) {
    __shared__ float As[32][68];    // 8.5 KB
    __shared__ float Ws[64 * 128];  // 32 KB: W1, then W2
    __shared__ float Hs[32][132];   // 16.5 KB
    const int tid = threadIdx.x;
    const int row0 = blockIdx.x * 32;
    const int ty = tid >> 4;        // 0..15 -> rows ty*2, ty*2+1
    const int tx = tid & 15;        // 0..15

    // stage A tile (32x64): 512 float4, 2/thread
    for (int l = 0; l < 2; ++l) {
        int idx = l * 256 + tid;
        int r = idx >> 4, cv = idx & 15;
        int gr = row0 + r;
        float4 v = make_float4(0.f, 0.f, 0.f, 0.f);
        if (gr < M) v = *(const float4*)&G[(long)gr * DIM + cv * 4];
        *(float4*)&As[r][cv * 4] = v;
    }
    // stage W1 (8192 floats): 8 float4/thread
    for (int l = 0; l < 8; ++l) {
        int idx = (l * 256 + tid) * 4;
        *(float4*)&Ws[idx] = *(const float4*)&W1[idx];
    }
    __syncthreads();

    // stage 1: h(32x128) = As @ W1 + b1, relu -> Hs. rows ty*2+{0,1}, cols tx*8..+7
    float4 acc0A = make_float4(0.f, 0.f, 0.f, 0.f), acc0B = acc0A;
    float4 acc1A = acc0A, acc1B = acc0A;
    for (int k4 = 0; k4 < 64; k4 += 4) {
        float4 a0 = *(const float4*)&As[ty * 2 + 0][k4];
        float4 a1 = *(const float4*)&As[ty * 2 + 1][k4];
        #pragma unroll
        for (int kk = 0; kk < 4; ++kk) {
            float a0k = (&a0.x)[kk];
            float a1k = (&a1.x)[kk];
            const float* wr = &Ws[(k4 + kk) * 128 + tx * 8];
            float4 wA = *(const float4*)wr;
            float4 wB = *(const float4*)(wr + 4);
            acc0A.x += a0k * wA.x; acc0A.y += a0k * wA.y; acc0A.z += a0k * wA.z; acc0A.w += a0k * wA.w;
            acc0B.x += a0k * wB.x; acc0B.y += a0k * wB.y; acc0B.z += a0k * wB.z; acc0B.w += a0k * wB.w;
            acc1A.x += a1k * wA.x; acc1A.y += a1k * wA.y; acc1A.z += a1k * wA.z; acc1A.w += a1k * wA.w;
            acc1B.x += a1k * wB.x; acc1B.y += a1k * wB.y; acc1B.z += a1k * wB.z; acc1B.w += a1k * wB.w;
        }
    }
    {
        float4 bA = *(const float4*)&b1[tx * 8];
        float4 bB = *(const float4*)&b1[tx * 8 + 4];
        float4 h0A = make_float4(fmaxf(acc0A.x + bA.x, 0.f), fmaxf(acc0A.y + bA.y, 0.f),
                                 fmaxf(acc0A.z + bA.z, 0.f), fmaxf(acc0A.w + bA.w, 0.f));
        float4 h0B = make_float4(fmaxf(acc0B.x + bB.x, 0.f), fmaxf(acc0B.y + bB.y, 0.f),
                                 fmaxf(acc0B.z + bB.z, 0.f), fmaxf(acc0B.w + bB.w, 0.f));
        float4 h1A = make_float4(fmaxf(acc1A.x + bA.x, 0.f), fmaxf(acc1A.y + bA.y, 0.f),
                                 fmaxf(acc1A.z + bA.z, 0.f), fmaxf(acc1A.w + bA.w, 0.f));
        float4 h1B = make_float4(fmaxf(acc1B.x + bB.x, 0.f), fmaxf(acc1B.y + bB.y, 0.f),
                                 fmaxf(acc1B.z + bB.z, 0.f), fmaxf(acc1B.w + bB.w, 0.f));
        *(float4*)&Hs[ty * 2 + 0][tx * 8 + 0] = h0A;
        *(float4*)&Hs[ty * 2 + 0][tx * 8 + 4] = h0B;
        *(float4*)&Hs[ty * 2 + 1][tx * 8 + 0] = h1A;
        *(float4*)&Hs[ty * 2 + 1][tx * 8 + 4] = h1B;
    }
    __syncthreads();   // Hs complete; W1 reads done

    // stage W2 (128x64 = 8192 floats) over W1's LDS
    for (int l = 0; l < 8; ++l) {
        int idx = (l * 256 + tid) * 4;
        *(float4*)&Ws[idx] = *(const float4*)&W2[idx];
    }
    __syncthreads();

    // stage 2: t(32x64) = Hs @ W2. rows ty*2+{0,1}, cols tx*4..+3
    float4 o0 = make_float4(0.f, 0.f, 0.f, 0.f), o1 = o0;
    for (int k4 = 0; k4 < 128; k4 += 4) {
        float4 a0 = *(const float4*)&Hs[ty * 2 + 0][k4];
        float4 a1 = *(const float4*)&Hs[ty * 2 + 1][k4];
        #pragma unroll
        for (int kk = 0; kk < 4; ++kk) {
            float a0k = (&a0.x)[kk];
            float a1k = (&a1.x)[kk];
            float4 w = *(const float4*)&Ws[(k4 + kk) * 64 + tx * 4];
            o0.x += a0k * w.x; o0.y += a0k * w.y; o0.z += a0k * w.z; o0.w += a0k * w.w;
            o1.x += a1k * w.x; o1.y += a1k * w.y; o1.z += a1k * w.z; o1.w += a1k * w.w;
        }
    }
    {
        int gr0 = row0 + ty * 2 + 0;
        int gr1 = row0 + ty * 2 + 1;
        if (gr0 < M) *(float4*)&T[(long)gr0 * DIM + tx * 4] = o0;
        if (gr1 < M) *(float4*)&T[(long)gr1 * DIM + tx * 4] = o1;
    }
}

// ---------------- R2 fallback path (atomic scatter) ----------------
__global__ __launch_bounds__(256) void k_init_deg(float* deg, int n) {
    int i = blockIdx.x * 256 + threadIdx.x;
    if (i < n) deg[i] = 1.0f;
}
__global__ __launch_bounds__(256) void k_count_deg(const int* __restrict__ ei, float* deg, int E) {
    int e = blockIdx.x * 256 + threadIdx.x;
    if (e < E) atomAddF(&deg[ei[E + e]], 1.0f);
}
__global__ __launch_bounds__(256) void k_rsqrt(float* deg, int n) {
    int i = blockIdx.x * 256 + threadIdx.x;
    if (i < n) deg[i] = rsqrtf(deg[i]);
}
template<bool BIAS>
__global__ __launch_bounds__(256) void k_self(const float* __restrict__ src,
                                              const float* __restrict__ dinv,
                                              const float* __restrict__ b,
                                              float* __restrict__ out, int n) {
    int g = blockIdx.x * 256 + threadIdx.x;
    int i = g >> 4, c = g & 15;
    if (i >= n) return;
    float di = dinv[i];
    float s = di * di;
    float4 v = *(const float4*)&src[(long)i * DIM + c * 4];
    float4 r = make_float4(v.x * s, v.y * s, v.z * s, v.w * s);
    if (BIAS) {
        float4 bv = *(const float4*)&b[c * 4];
        r.x += bv.x; r.y += bv.y; r.z += bv.z; r.w += bv.w;
    }
    *(float4*)&out[(long)i * DIM + c * 4] = r;
}
__global__ __launch_bounds__(256) void k_edge_agg(const int* __restrict__ ei,
                                                  const float* __restrict__ dinv,
                                                  const float* __restrict__ h,
                                                  float* __restrict__ out, int E) {
    int t = threadIdx.x;
    int e = blockIdx.x * 16 + (t >> 4);
    if (e >= E) return;
    int lane = t & 15;
    int s = ei[e];
    int d = ei[E + e];
    float norm = dinv[s] * dinv[d];
    float4 hv = *(const float4*)&h[(long)s * DIM + lane * 4];
    float* o = &out[(long)d * DIM + lane * 4];
    atomAddF(o + 0, hv.x * norm);
    atomAddF(o + 1, hv.y * norm);
    atomAddF(o + 2, hv.z * norm);
    atomAddF(o + 3, hv.w * norm);
}

extern "C" void kernel_launch(void* const* d_in, const int* in_sizes, int n_in,
                              void* d_out, int out_size, void* d_ws, size_t ws_size,
                              hipStream_t stream) {
    const float* x  = (const float*)d_in[0];
    const int*   ei = (const int*)d_in[1];   // [2,E] int32
    const float* W1 = (const float*)d_in[2];
    const float* b1 = (const float*)d_in[3];
    const float* W2 = (const float*)d_in[4];
    const float* b2 = (const float*)d_in[5];
    float* out = (float*)d_out;

    const int N = in_sizes[0] / DIM;   // 100000
    const int E = in_sizes[1] / 2;     // 1600000

    const int gn  = (N + 255) / 256;
    const int ge  = (E + 255) / 256;
    const int gagg = (N + 15) / 16;
    const int gmlp = (N + 31) / 32;

    // CSR layout in ws (256B-aligned bump)
    size_t off = 0;
    auto bump = [&](size_t bytes) { size_t o = off; off = (off + bytes + 255) & ~(size_t)255; return o; };
    size_t o_dinv    = bump((size_t)N * 4);
    size_t o_rowptr  = bump((size_t)(N + 1) * 4);
    size_t o_cursor  = bump((size_t)N * 4);        // doubles as counts
    size_t o_part    = bump(4096 * 4);
    size_t o_col     = bump((size_t)E * 4);
    size_t o_buf     = bump((size_t)N * DIM * 4);
    size_t need_csr  = off;

    char* ws = (char*)d_ws;

    if (ws_size >= need_csr) {
        // -------- CSR path --------
        float* dinv   = (float*)(ws + o_dinv);
        int*   rowptr = (int*)(ws + o_rowptr);
        int*   cursor = (int*)(ws + o_cursor);
        int*   part   = (int*)(ws + o_part);
        int*   col    = (int*)(ws + o_col);
        float* buf    = (float*)(ws + o_buf);

        k_zero_i<<<gn, 256, 0, stream>>>(cursor, N);
        k_hist<<<ge, 256, 0, stream>>>(ei, cursor, E);
        k_scan1<<<gn, 256, 0, stream>>>(cursor, rowptr, part, N);
        k_scan2<<<1, 1024, 0, stream>>>(part, gn);
        k_scan3<<<gn, 256, 0, stream>>>(rowptr, part, N, E);
        k_dinv_copy<<<gn, 256, 0, stream>>>(rowptr, dinv, cursor, N);
        k_scatter<<<ge, 256, 0, stream>>>(ei, cursor, col, E);

        // d_out = Ahat x
        k_agg_csr<false><<<gagg, 256, 0, stream>>>(rowptr, col, dinv, x, nullptr, out, N);
        // buf = relu(d_out @ W1 + b1) @ W2
        k_fused_mlp<<<gmlp, 256, 0, stream>>>(out, W1, b1, W2, buf, N);
        // d_out = Ahat buf + b2
        k_agg_csr<true><<<gagg, 256, 0, stream>>>(rowptr, col, dinv, buf, b2, out, N);
    } else {
        // -------- R2 fallback (atomic scatter) --------
        float* dinv = (float*)ws;
        float* buf  = (float*)(ws + 512 * 1024);
        int gl = ((long)N * 16 + 255) / 256;
        int gedge = (E + 15) / 16;

        k_init_deg<<<gn, 256, 0, stream>>>(dinv, N);
        k_count_deg<<<ge, 256, 0, stream>>>(ei, dinv, E);
        k_rsqrt<<<gn, 256, 0, stream>>>(dinv, N);

        k_self<false><<<gl, 256, 0, stream>>>(x, dinv, nullptr, buf, N);
        k_edge_agg<<<gedge, 256, 0, stream>>>(ei, dinv, x, buf, E);
        k_fused_mlp<<<gmlp, 256, 0, stream>>>(buf, W1, b1, W2, buf, N);
        k_self<true><<<gl, 256, 0, stream>>>(buf, dinv, b2, out, N);
        k_edge_agg<<<gedge, 256, 0, stream>>>(ei, dinv, buf, out, E);
    }
}

// Round 5
// 444.797 us; speedup vs baseline: 7.4518x; 1.1322x over previous
//
#include <hip/hip_runtime.h>

// GCN 2-layer: out = Ahat( relu( Ahat(x) W1 + b1 ) W2 ) + b2, Ahat = D^-1/2 (A+I) D^-1/2.
// Ahat(x W1) = (Ahat x) W1 -> aggregate in 64-dim space both times.
// N=100000, E=1.6M, dims 64->128->64.
//
// R4 post-mortem: k_scatter write-drain bound (WRITE_SIZE 106MB = 64B/write line
// amplification, 136us). R5: 8-pass dst-partitioned scatter -> per-pass col
// window 0.8MB stays L2-resident, lines fill before eviction.

#define DIM 64

__device__ __forceinline__ void atomAddF(float* p, float v) {
    unsafeAtomicAdd(p, v);
}

// ---------------- CSR build ----------------
__global__ __launch_bounds__(256) void k_zero_i(int* p, int n) {
    int i = blockIdx.x * 256 + threadIdx.x;
    if (i < n) p[i] = 0;
}
__global__ __launch_bounds__(256) void k_hist(const int* __restrict__ ei, int* counts, int E) {
    int e = blockIdx.x * 256 + threadIdx.x;
    if (e < E) atomicAdd(&counts[ei[E + e]], 1);   // in-degree of dst
}
__global__ __launch_bounds__(256) void k_scan1(const int* __restrict__ counts,
                                               int* __restrict__ row_ptr,
                                               int* __restrict__ partials, int n) {
    __shared__ int s[256];
    int tid = threadIdx.x;
    int i = blockIdx.x * 256 + tid;
    int v = (i < n) ? counts[i] : 0;
    s[tid] = v; __syncthreads();
    for (int off = 1; off < 256; off <<= 1) {
        int t = (tid >= off) ? s[tid - off] : 0;
        __syncthreads();
        s[tid] += t;
        __syncthreads();
    }
    if (i < n) row_ptr[i] = s[tid] - v;            // exclusive
    if (tid == 255) partials[blockIdx.x] = s[255]; // inclusive total
}
__global__ __launch_bounds__(1024) void k_scan2(int* partials, int nb) {
    __shared__ int s[1024];
    int tid = threadIdx.x;
    int v = (tid < nb) ? partials[tid] : 0;
    s[tid] = v; __syncthreads();
    for (int off = 1; off < 1024; off <<= 1) {
        int t = (tid >= off) ? s[tid - off] : 0;
        __syncthreads();
        s[tid] += t;
        __syncthreads();
    }
    if (tid < nb) partials[tid] = s[tid] - v;
}
__global__ __launch_bounds__(256) void k_scan3(int* __restrict__ row_ptr,
                                               const int* __restrict__ partials, int n, int E) {
    int i = blockIdx.x * 256 + threadIdx.x;
    if (i < n) row_ptr[i] += partials[blockIdx.x];
    if (i == 0) row_ptr[n] = E;
}
__global__ __launch_bounds__(256) void k_dinv_copy(const int* __restrict__ row_ptr,
                                                   float* __restrict__ dinv,
                                                   int* __restrict__ cursor, int n) {
    int i = blockIdx.x * 256 + threadIdx.x;
    if (i < n) {
        int r0 = row_ptr[i];
        dinv[i] = rsqrtf(1.0f + (float)(row_ptr[i + 1] - r0));  // +1 self-loop
        cursor[i] = r0;
    }
}
// 8-pass dst-partitioned scatter: pass-major blockIdx so co-resident blocks share
// a ~0.8MB col window (L2-resident -> write lines fill before eviction).
template<int NPASS>
__global__ __launch_bounds__(256) void k_scatter_mp(const int* __restrict__ ei,
                                                    int* __restrict__ cursor,
                                                    int* __restrict__ col,
                                                    int E, int N, int nchunks) {
    int pass  = blockIdx.x / nchunks;
    int chunk = blockIdx.x - pass * nchunks;
    int e = chunk * 256 + threadIdx.x;
    if (e >= E) return;
    int d = ei[E + e];
    const int span = (N + NPASS - 1) / NPASS;
    int lo = pass * span;
    if (d >= lo && d < lo + span) {
        int pos = atomicAdd(&cursor[d], 1);
        col[pos] = ei[e];   // src
    }
}

// ---------------- CSR aggregation (atomic-free) ----------------
// out[d] = dinv[d] * ( dinv[d]*h[d] + sum_{s in N(d)} dinv[s]*h[s] ) [+ b]
template<bool BIAS>
__global__ __launch_bounds__(256) void k_agg_csr(const int* __restrict__ row_ptr,
                                                 const int* __restrict__ col,
                                                 const float* __restrict__ dinv,
                                                 const float* __restrict__ h,
                                                 const float* __restrict__ b,
                                                 float* __restrict__ out, int n) {
    int g = blockIdx.x * 16 + (threadIdx.x >> 4);
    if (g >= n) return;
    int lane = threadIdx.x & 15;
    const float4* h4 = (const float4*)h;
    float di = dinv[g];
    float4 hv = h4[(long)g * 16 + lane];
    float4 acc = make_float4(hv.x * di, hv.y * di, hv.z * di, hv.w * di);  // self term
    int e1 = row_ptr[g + 1];
    for (int e = row_ptr[g]; e < e1; ++e) {
        int s = col[e];
        float ds = dinv[s];
        float4 v = h4[(long)s * 16 + lane];
        acc.x += ds * v.x; acc.y += ds * v.y; acc.z += ds * v.z; acc.w += ds * v.w;
    }
    acc.x *= di; acc.y *= di; acc.z *= di; acc.w *= di;
    if (BIAS) {
        float4 bv = ((const float4*)b)[lane];
        acc.x += bv.x; acc.y += bv.y; acc.z += bv.z; acc.w += bv.w;
    }
    ((float4*)out)[(long)g * 16 + lane] = acc;
}

// ---------------- fused MLP: T = relu(G @ W1 + b1) @ W2 ----------------
__global__ __launch_bounds__(256) void k_fused_mlp(const float* __restrict__ G,  // [N,64]
                                                   const float* __restrict__ W1, // [64,128]
                                                   const float* __restrict__ b1, // [128]
                                                   const float* __restrict__ W2, // [128,64]
                                                   float* __restrict__ T,        // [N,64]
                                                   int M) {
    __shared__ float As[32][68];
    __shared__ float Ws[64 * 128];  // W1, then W2
    __shared__ float Hs[32][132];
    const int tid = threadIdx.x;
    const int row0 = blockIdx.x * 32;
    const int ty = tid >> 4;
    const int tx = tid & 15;

    for (int l = 0; l < 2; ++l) {
        int idx = l * 256 + tid;
        int r = idx >> 4, cv = idx & 15;
        int gr = row0 + r;
        float4 v = make_float4(0.f, 0.f, 0.f, 0.f);
        if (gr < M) v = *(const float4*)&G[(long)gr * DIM + cv * 4];
        *(float4*)&As[r][cv * 4] = v;
    }
    for (int l = 0; l < 8; ++l) {
        int idx = (l * 256 + tid) * 4;
        *(float4*)&Ws[idx] = *(const float4*)&W1[idx];
    }
    __syncthreads();

    float4 acc0A = make_float4(0.f, 0.f, 0.f, 0.f), acc0B = acc0A;
    float4 acc1A = acc0A, acc1B = acc0A;
    for (int k4 = 0; k4 < 64; k4 += 4) {
        float4 a0 = *(const float4*)&As[ty * 2 + 0][k4];
        float4 a1 = *(const float4*)&As[ty * 2 + 1][k4];
        #pragma unroll
        for (int kk = 0; kk < 4; ++kk) {
            float a0k = (&a0.x)[kk];
            float a1k = (&a1.x)[kk];
            const float* wr = &Ws[(k4 + kk) * 128 + tx * 8];
            float4 wA = *(const float4*)wr;
            float4 wB = *(const float4*)(wr + 4);
            acc0A.x += a0k * wA.x; acc0A.y += a0k * wA.y; acc0A.z += a0k * wA.z; acc0A.w += a0k * wA.w;
            acc0B.x += a0k * wB.x; acc0B.y += a0k * wB.y; acc0B.z += a0k * wB.z; acc0B.w += a0k * wB.w;
            acc1A.x += a1k * wA.x; acc1A.y += a1k * wA.y; acc1A.z += a1k * wA.z; acc1A.w += a1k * wA.w;
            acc1B.x += a1k * wB.x; acc1B.y += a1k * wB.y; acc1B.z += a1k * wB.z; acc1B.w += a1k * wB.w;
        }
    }
    {
        float4 bA = *(const float4*)&b1[tx * 8];
        float4 bB = *(const float4*)&b1[tx * 8 + 4];
        float4 h0A = make_float4(fmaxf(acc0A.x + bA.x, 0.f), fmaxf(acc0A.y + bA.y, 0.f),
                                 fmaxf(acc0A.z + bA.z, 0.f), fmaxf(acc0A.w + bA.w, 0.f));
        float4 h0B = make_float4(fmaxf(acc0B.x + bB.x, 0.f), fmaxf(acc0B.y + bB.y, 0.f),
                                 fmaxf(acc0B.z + bB.z, 0.f), fmaxf(acc0B.w + bB.w, 0.f));
        float4 h1A = make_float4(fmaxf(acc1A.x + bA.x, 0.f), fmaxf(acc1A.y + bA.y, 0.f),
                                 fmaxf(acc1A.z + bA.z, 0.f), fmaxf(acc1A.w + bA.w, 0.f));
        float4 h1B = make_float4(fmaxf(acc1B.x + bB.x, 0.f), fmaxf(acc1B.y + bB.y, 0.f),
                                 fmaxf(acc1B.z + bB.z, 0.f), fmaxf(acc1B.w + bB.w, 0.f));
        *(float4*)&Hs[ty * 2 + 0][tx * 8 + 0] = h0A;
        *(float4*)&Hs[ty * 2 + 0][tx * 8 + 4] = h0B;
        *(float4*)&Hs[ty * 2 + 1][tx * 8 + 0] = h1A;
        *(float4*)&Hs[ty * 2 + 1][tx * 8 + 4] = h1B;
    }
    __syncthreads();

    for (int l = 0; l < 8; ++l) {
        int idx = (l * 256 + tid) * 4;
        *(float4*)&Ws[idx] = *(const float4*)&W2[idx];
    }
    __syncthreads();

    float4 o0 = make_float4(0.f, 0.f, 0.f, 0.f), o1 = o0;
    for (int k4 = 0; k4 < 128; k4 += 4) {
        float4 a0 = *(const float4*)&Hs[ty * 2 + 0][k4];
        float4 a1 = *(const float4*)&Hs[ty * 2 + 1][k4];
        #pragma unroll
        for (int kk = 0; kk < 4; ++kk) {
            float a0k = (&a0.x)[kk];
            float a1k = (&a1.x)[kk];
            float4 w = *(const float4*)&Ws[(k4 + kk) * 64 + tx * 4];
            o0.x += a0k * w.x; o0.y += a0k * w.y; o0.z += a0k * w.z; o0.w += a0k * w.w;
            o1.x += a1k * w.x; o1.y += a1k * w.y; o1.z += a1k * w.z; o1.w += a1k * w.w;
        }
    }
    {
        int gr0 = row0 + ty * 2 + 0;
        int gr1 = row0 + ty * 2 + 1;
        if (gr0 < M) *(float4*)&T[(long)gr0 * DIM + tx * 4] = o0;
        if (gr1 < M) *(float4*)&T[(long)gr1 * DIM + tx * 4] = o1;
    }
}

// ---------------- R2 fallback path (atomic scatter) ----------------
__global__ __launch_bounds__(256) void k_init_deg(float* deg, int n) {
    int i = blockIdx.x * 256 + threadIdx.x;
    if (i < n) deg[i] = 1.0f;
}
__global__ __launch_bounds__(256) void k_count_deg(const int* __restrict__ ei, float* deg, int E) {
    int e = blockIdx.x * 256 + threadIdx.x;
    if (e < E) atomAddF(&deg[ei[E + e]], 1.0f);
}
__global__ __launch_bounds__(256) void k_rsqrt(float* deg, int n) {
    int i = blockIdx.x * 256 + threadIdx.x;
    if (i < n) deg[i] = rsqrtf(deg[i]);
}
template<bool BIAS>
__global__ __launch_bounds__(256) void k_self(const float* __restrict__ src,
                                              const float* __restrict__ dinv,
                                              const float* __restrict__ b,
                                              float* __restrict__ out, int n) {
    int g = blockIdx.x * 256 + threadIdx.x;
    int i = g >> 4, c = g & 15;
    if (i >= n) return;
    float di = dinv[i];
    float s = di * di;
    float4 v = *(const float4*)&src[(long)i * DIM + c * 4];
    float4 r = make_float4(v.x * s, v.y * s, v.z * s, v.w * s);
    if (BIAS) {
        float4 bv = *(const float4*)&b[c * 4];
        r.x += bv.x; r.y += bv.y; r.z += bv.z; r.w += bv.w;
    }
    *(float4*)&out[(long)i * DIM + c * 4] = r;
}
__global__ __launch_bounds__(256) void k_edge_agg(const int* __restrict__ ei,
                                                  const float* __restrict__ dinv,
                                                  const float* __restrict__ h,
                                                  float* __restrict__ out, int E) {
    int t = threadIdx.x;
    int e = blockIdx.x * 16 + (t >> 4);
    if (e >= E) return;
    int lane = t & 15;
    int s = ei[e];
    int d = ei[E + e];
    float norm = dinv[s] * dinv[d];
    float4 hv = *(const float4*)&h[(long)s * DIM + lane * 4];
    float* o = &out[(long)d * DIM + lane * 4];
    atomAddF(o + 0, hv.x * norm);
    atomAddF(o + 1, hv.y * norm);
    atomAddF(o + 2, hv.z * norm);
    atomAddF(o + 3, hv.w * norm);
}

extern "C" void kernel_launch(void* const* d_in, const int* in_sizes, int n_in,
                              void* d_out, int out_size, void* d_ws, size_t ws_size,
                              hipStream_t stream) {
    const float* x  = (const float*)d_in[0];
    const int*   ei = (const int*)d_in[1];   // [2,E] int32
    const float* W1 = (const float*)d_in[2];
    const float* b1 = (const float*)d_in[3];
    const float* W2 = (const float*)d_in[4];
    const float* b2 = (const float*)d_in[5];
    float* out = (float*)d_out;

    const int N = in_sizes[0] / DIM;   // 100000
    const int E = in_sizes[1] / 2;     // 1600000

    const int gn  = (N + 255) / 256;
    const int ge  = (E + 255) / 256;
    const int gagg = (N + 15) / 16;
    const int gmlp = (N + 31) / 32;

    // CSR layout in ws (256B-aligned bump)
    size_t off = 0;
    auto bump = [&](size_t bytes) { size_t o = off; off = (off + bytes + 255) & ~(size_t)255; return o; };
    size_t o_dinv    = bump((size_t)N * 4);
    size_t o_rowptr  = bump((size_t)(N + 1) * 4);
    size_t o_cursor  = bump((size_t)N * 4);        // doubles as counts
    size_t o_part    = bump(4096 * 4);
    size_t o_col     = bump((size_t)E * 4);
    size_t o_buf     = bump((size_t)N * DIM * 4);
    size_t need_csr  = off;

    char* ws = (char*)d_ws;

    if (ws_size >= need_csr) {
        // -------- CSR path --------
        float* dinv   = (float*)(ws + o_dinv);
        int*   rowptr = (int*)(ws + o_rowptr);
        int*   cursor = (int*)(ws + o_cursor);
        int*   part   = (int*)(ws + o_part);
        int*   col    = (int*)(ws + o_col);
        float* buf    = (float*)(ws + o_buf);

        k_zero_i<<<gn, 256, 0, stream>>>(cursor, N);
        k_hist<<<ge, 256, 0, stream>>>(ei, cursor, E);
        k_scan1<<<gn, 256, 0, stream>>>(cursor, rowptr, part, N);
        k_scan2<<<1, 1024, 0, stream>>>(part, gn);
        k_scan3<<<gn, 256, 0, stream>>>(rowptr, part, N, E);
        k_dinv_copy<<<gn, 256, 0, stream>>>(rowptr, dinv, cursor, N);
        k_scatter_mp<8><<<8 * ge, 256, 0, stream>>>(ei, cursor, col, E, N, ge);

        // d_out = Ahat x
        k_agg_csr<false><<<gagg, 256, 0, stream>>>(rowptr, col, dinv, x, nullptr, out, N);
        // buf = relu(d_out @ W1 + b1) @ W2
        k_fused_mlp<<<gmlp, 256, 0, stream>>>(out, W1, b1, W2, buf, N);
        // d_out = Ahat buf + b2
        k_agg_csr<true><<<gagg, 256, 0, stream>>>(rowptr, col, dinv, buf, b2, out, N);
    } else {
        // -------- R2 fallback (atomic scatter) --------
        float* dinv = (float*)ws;
        float* buf  = (float*)(ws + 512 * 1024);
        int gl = ((long)N * 16 + 255) / 256;
        int gedge = (E + 15) / 16;

        k_init_deg<<<gn, 256, 0, stream>>>(dinv, N);
        k_count_deg<<<ge, 256, 0, stream>>>(ei, dinv, E);
        k_rsqrt<<<gn, 256, 0, stream>>>(dinv, N);

        k_self<false><<<gl, 256, 0, stream>>>(x, dinv, nullptr, buf, N);
        k_edge_agg<<<gedge, 256, 0, stream>>>(ei, dinv, x, buf, E);
        k_fused_mlp<<<gmlp, 256, 0, stream>>>(buf, W1, b1, W2, buf, N);
        k_self<true><<<gl, 256, 0, stream>>>(buf, dinv, b2, out, N);
        k_edge_agg<<<gedge, 256, 0, stream>>>(ei, dinv, buf, out, E);
    }
}

// Round 6
// 378.661 us; speedup vs baseline: 8.7534x; 1.1747x over previous
//
#include <hip/hip_runtime.h>

// GCN 2-layer: out = Ahat( relu( Ahat(x) W1 + b1 ) W2 ) + b2, Ahat = D^-1/2 (A+I) D^-1/2.
// Ahat(x W1) = (Ahat x) W1 -> aggregate in 64-dim space both times.
// N=100000, E=1.6M, dims 64->128->64.
//
// R5 post-mortem: multi-pass scatter still wrote 86MB (col lines written by edges
// spread across XCDs -> partial-line evictions; window size was not the issue,
// line OWNERSHIP is). R6: tile multisplit into 256 exact-sized dst-range buckets
// (coalesced pair writes), then one-block-per-bucket scatter (single-XCD col
// window, LDS cursors). Exact regions come free from row_ptr. agg loop unroll x2.

#define DIM 64
#define NB 256          // dst-range buckets
#define SPAN 391        // ceil(100000/256); NB*SPAN >= N
#define BK_TILE 4096
#define BK_PER 16       // edges per thread in k_bucket

__device__ __forceinline__ void atomAddF(float* p, float v) {
    unsafeAtomicAdd(p, v);
}

// ---------------- CSR build ----------------
__global__ __launch_bounds__(256) void k_zero_i(int* p, int n) {
    int i = blockIdx.x * 256 + threadIdx.x;
    if (i < n) p[i] = 0;
}
__global__ __launch_bounds__(256) void k_hist(const int* __restrict__ ei, int* counts, int E) {
    int e = blockIdx.x * 256 + threadIdx.x;
    if (e < E) atomicAdd(&counts[ei[E + e]], 1);   // in-degree of dst
}
__global__ __launch_bounds__(256) void k_scan1(const int* __restrict__ counts,
                                               int* __restrict__ row_ptr,
                                               int* __restrict__ partials, int n) {
    __shared__ int s[256];
    int tid = threadIdx.x;
    int i = blockIdx.x * 256 + tid;
    int v = (i < n) ? counts[i] : 0;
    s[tid] = v; __syncthreads();
    for (int off = 1; off < 256; off <<= 1) {
        int t = (tid >= off) ? s[tid - off] : 0;
        __syncthreads();
        s[tid] += t;
        __syncthreads();
    }
    if (i < n) row_ptr[i] = s[tid] - v;            // exclusive
    if (tid == 255) partials[blockIdx.x] = s[255]; // inclusive total
}
__global__ __launch_bounds__(1024) void k_scan2(int* partials, int nb) {
    __shared__ int s[1024];
    int tid = threadIdx.x;
    int v = (tid < nb) ? partials[tid] : 0;
    s[tid] = v; __syncthreads();
    for (int off = 1; off < 1024; off <<= 1) {
        int t = (tid >= off) ? s[tid - off] : 0;
        __syncthreads();
        s[tid] += t;
        __syncthreads();
    }
    if (tid < nb) partials[tid] = s[tid] - v;
}
__global__ __launch_bounds__(256) void k_scan3(int* __restrict__ row_ptr,
                                               const int* __restrict__ partials, int n, int E) {
    int i = blockIdx.x * 256 + threadIdx.x;
    if (i < n) row_ptr[i] += partials[blockIdx.x];
    if (i == 0) row_ptr[n] = E;
}
__global__ __launch_bounds__(256) void k_dinv(const int* __restrict__ row_ptr,
                                              float* __restrict__ dinv, int n) {
    int i = blockIdx.x * 256 + threadIdx.x;
    if (i < n) dinv[i] = rsqrtf(1.0f + (float)(row_ptr[i + 1] - row_ptr[i]));  // +1 self-loop
}
// gcur[b] = start of bucket b's exact region in col/pairs space
__global__ __launch_bounds__(NB) void k_bucket_base(const int* __restrict__ row_ptr,
                                                    int* __restrict__ gcur) {
    int b = threadIdx.x;
    gcur[b] = row_ptr[b * SPAN];   // b*SPAN <= 255*391 = 99705 < N
}

// Phase A: tile multisplit. Bucket-grouped (src,dst) pairs, coalesced writes into
// exact per-bucket regions (regions sized by row_ptr; no overflow possible).
__global__ __launch_bounds__(256) void k_bucket(const int* __restrict__ ei,
                                                int* __restrict__ gcur,
                                                uint2* __restrict__ pairs, int E) {
    __shared__ int scn[NB];               // hist -> inclusive scan
    __shared__ int run[NB];               // running local cursor
    __shared__ int lbase[NB];             // local exclusive base
    __shared__ int gbase[NB];             // global reserved base
    __shared__ uint2 stage[BK_TILE];      // 32 KB
    __shared__ unsigned char bkt[BK_TILE];// 4 KB
    const int tid = threadIdx.x;
    const int base = blockIdx.x * BK_TILE;

    scn[tid] = 0;
    __syncthreads();

    int sv[BK_PER], dv[BK_PER], bv[BK_PER];
    #pragma unroll
    for (int j = 0; j < BK_PER; ++j) {
        int e = base + j * 256 + tid;
        if (e < E) {
            sv[j] = ei[e];
            dv[j] = ei[E + e];
            bv[j] = (int)((unsigned)dv[j] / (unsigned)SPAN);
            atomicAdd(&scn[bv[j]], 1);
        } else bv[j] = -1;
    }
    __syncthreads();
    int c = scn[tid];                      // count for bucket==tid
    for (int off = 1; off < 256; off <<= 1) {
        int t = (tid >= off) ? scn[tid - off] : 0;
        __syncthreads();
        scn[tid] += t;
        __syncthreads();
    }
    int ex = scn[tid] - c;                 // exclusive
    lbase[tid] = ex;
    run[tid] = ex;
    if (c > 0) gbase[tid] = atomicAdd(&gcur[tid], c);
    __syncthreads();

    #pragma unroll
    for (int j = 0; j < BK_PER; ++j) {
        if (bv[j] >= 0) {
            int p = atomicAdd(&run[bv[j]], 1);
            stage[p] = make_uint2((unsigned)sv[j], (unsigned)dv[j]);
            bkt[p] = (unsigned char)bv[j];
        }
    }
    __syncthreads();

    int total = min(BK_TILE, E - base);
    for (int i = tid; i < total; i += 256) {
        int bb = bkt[i];
        pairs[gbase[bb] + (i - lbase[bb])] = stage[i];
    }
}

// Phase B: one block per bucket. All col writes for the bucket's window come
// from one CU (one XCD L2) -> full-line writes. LDS cursors from row_ptr.
__global__ __launch_bounds__(256) void k_scatter_bkt(const uint2* __restrict__ pairs,
                                                     const int* __restrict__ row_ptr,
                                                     int* __restrict__ col, int N) {
    __shared__ int lcur[SPAN];
    const int tid = threadIdx.x;
    const int b = blockIdx.x;
    const int lo = b * SPAN;
    const int hi = min(lo + SPAN, N);
    const int nn = hi - lo;
    for (int i = tid; i < nn; i += 256) lcur[i] = row_ptr[lo + i];
    __syncthreads();
    const int p0 = row_ptr[lo];
    const int p1 = row_ptr[hi];
    for (int i = p0 + tid; i < p1; i += 256) {
        uint2 pr = pairs[i];
        int pos = atomicAdd(&lcur[(int)pr.y - lo], 1);
        col[pos] = (int)pr.x;
    }
}

// ---------------- CSR aggregation (atomic-free, unroll x2) ----------------
// out[d] = dinv[d] * ( dinv[d]*h[d] + sum_{s in N(d)} dinv[s]*h[s] ) [+ b]
template<bool BIAS>
__global__ __launch_bounds__(256) void k_agg_csr(const int* __restrict__ row_ptr,
                                                 const int* __restrict__ col,
                                                 const float* __restrict__ dinv,
                                                 const float* __restrict__ h,
                                                 const float* __restrict__ b,
                                                 float* __restrict__ out, int n) {
    int g = blockIdx.x * 16 + (threadIdx.x >> 4);
    if (g >= n) return;
    int lane = threadIdx.x & 15;
    const float4* h4 = (const float4*)h;
    float di = dinv[g];
    float4 hv = h4[(long)g * 16 + lane];
    float4 accA = make_float4(hv.x * di, hv.y * di, hv.z * di, hv.w * di);  // self term
    float4 accB = make_float4(0.f, 0.f, 0.f, 0.f);
    int e0 = row_ptr[g], e1 = row_ptr[g + 1];
    int e = e0;
    for (; e + 2 <= e1; e += 2) {
        int sA = col[e], sB = col[e + 1];
        float dA = dinv[sA], dB = dinv[sB];
        float4 vA = h4[(long)sA * 16 + lane];
        float4 vB = h4[(long)sB * 16 + lane];
        accA.x += dA * vA.x; accA.y += dA * vA.y; accA.z += dA * vA.z; accA.w += dA * vA.w;
        accB.x += dB * vB.x; accB.y += dB * vB.y; accB.z += dB * vB.z; accB.w += dB * vB.w;
    }
    if (e < e1) {
        int sA = col[e];
        float dA = dinv[sA];
        float4 vA = h4[(long)sA * 16 + lane];
        accA.x += dA * vA.x; accA.y += dA * vA.y; accA.z += dA * vA.z; accA.w += dA * vA.w;
    }
    accA.x = (accA.x + accB.x) * di; accA.y = (accA.y + accB.y) * di;
    accA.z = (accA.z + accB.z) * di; accA.w = (accA.w + accB.w) * di;
    if (BIAS) {
        float4 bv = ((const float4*)b)[lane];
        accA.x += bv.x; accA.y += bv.y; accA.z += bv.z; accA.w += bv.w;
    }
    ((float4*)out)[(long)g * 16 + lane] = accA;
}

// ---------------- fused MLP: T = relu(G @ W1 + b1) @ W2 ----------------
__global__ __launch_bounds__(256) void k_fused_mlp(const float* __restrict__ G,  // [N,64]
                                                   const float* __restrict__ W1, // [64,128]
                                                   const float* __restrict__ b1, // [128]
                                                   const float* __restrict__ W2, // [128,64]
                                                   float* __restrict__ T,        // [N,64]
                                                   int M) {
    __shared__ float As[32][68];
    __shared__ float Ws[64 * 128];  // W1, then W2
    __shared__ float Hs[32][132];
    const int tid = threadIdx.x;
    const int row0 = blockIdx.x * 32;
    const int ty = tid >> 4;
    const int tx = tid & 15;

    for (int l = 0; l < 2; ++l) {
        int idx = l * 256 + tid;
        int r = idx >> 4, cv = idx & 15;
        int gr = row0 + r;
        float4 v = make_float4(0.f, 0.f, 0.f, 0.f);
        if (gr < M) v = *(const float4*)&G[(long)gr * DIM + cv * 4];
        *(float4*)&As[r][cv * 4] = v;
    }
    for (int l = 0; l < 8; ++l) {
        int idx = (l * 256 + tid) * 4;
        *(float4*)&Ws[idx] = *(const float4*)&W1[idx];
    }
    __syncthreads();

    float4 acc0A = make_float4(0.f, 0.f, 0.f, 0.f), acc0B = acc0A;
    float4 acc1A = acc0A, acc1B = acc0A;
    for (int k4 = 0; k4 < 64; k4 += 4) {
        float4 a0 = *(const float4*)&As[ty * 2 + 0][k4];
        float4 a1 = *(const float4*)&As[ty * 2 + 1][k4];
        #pragma unroll
        for (int kk = 0; kk < 4; ++kk) {
            float a0k = (&a0.x)[kk];
            float a1k = (&a1.x)[kk];
            const float* wr = &Ws[(k4 + kk) * 128 + tx * 8];
            float4 wA = *(const float4*)wr;
            float4 wB = *(const float4*)(wr + 4);
            acc0A.x += a0k * wA.x; acc0A.y += a0k * wA.y; acc0A.z += a0k * wA.z; acc0A.w += a0k * wA.w;
            acc0B.x += a0k * wB.x; acc0B.y += a0k * wB.y; acc0B.z += a0k * wB.z; acc0B.w += a0k * wB.w;
            acc1A.x += a1k * wA.x; acc1A.y += a1k * wA.y; acc1A.z += a1k * wA.z; acc1A.w += a1k * wA.w;
            acc1B.x += a1k * wB.x; acc1B.y += a1k * wB.y; acc1B.z += a1k * wB.z; acc1B.w += a1k * wB.w;
        }
    }
    {
        float4 bA = *(const float4*)&b1[tx * 8];
        float4 bB = *(const float4*)&b1[tx * 8 + 4];
        float4 h0A = make_float4(fmaxf(acc0A.x + bA.x, 0.f), fmaxf(acc0A.y + bA.y, 0.f),
                                 fmaxf(acc0A.z + bA.z, 0.f), fmaxf(acc0A.w + bA.w, 0.f));
        float4 h0B = make_float4(fmaxf(acc0B.x + bB.x, 0.f), fmaxf(acc0B.y + bB.y, 0.f),
                                 fmaxf(acc0B.z + bB.z, 0.f), fmaxf(acc0B.w + bB.w, 0.f));
        float4 h1A = make_float4(fmaxf(acc1A.x + bA.x, 0.f), fmaxf(acc1A.y + bA.y, 0.f),
                                 fmaxf(acc1A.z + bA.z, 0.f), fmaxf(acc1A.w + bA.w, 0.f));
        float4 h1B = make_float4(fmaxf(acc1B.x + bB.x, 0.f), fmaxf(acc1B.y + bB.y, 0.f),
                                 fmaxf(acc1B.z + bB.z, 0.f), fmaxf(acc1B.w + bB.w, 0.f));
        *(float4*)&Hs[ty * 2 + 0][tx * 8 + 0] = h0A;
        *(float4*)&Hs[ty * 2 + 0][tx * 8 + 4] = h0B;
        *(float4*)&Hs[ty * 2 + 1][tx * 8 + 0] = h1A;
        *(float4*)&Hs[ty * 2 + 1][tx * 8 + 4] = h1B;
    }
    __syncthreads();

    for (int l = 0; l < 8; ++l) {
        int idx = (l * 256 + tid) * 4;
        *(float4*)&Ws[idx] = *(const float4*)&W2[idx];
    }
    __syncthreads();

    float4 o0 = make_float4(0.f, 0.f, 0.f, 0.f), o1 = o0;
    for (int k4 = 0; k4 < 128; k4 += 4) {
        float4 a0 = *(const float4*)&Hs[ty * 2 + 0][k4];
        float4 a1 = *(const float4*)&Hs[ty * 2 + 1][k4];
        #pragma unroll
        for (int kk = 0; kk < 4; ++kk) {
            float a0k = (&a0.x)[kk];
            float a1k = (&a1.x)[kk];
            float4 w = *(const float4*)&Ws[(k4 + kk) * 64 + tx * 4];
            o0.x += a0k * w.x; o0.y += a0k * w.y; o0.z += a0k * w.z; o0.w += a0k * w.w;
            o1.x += a1k * w.x; o1.y += a1k * w.y; o1.z += a1k * w.z; o1.w += a1k * w.w;
        }
    }
    {
        int gr0 = row0 + ty * 2 + 0;
        int gr1 = row0 + ty * 2 + 1;
        if (gr0 < M) *(float4*)&T[(long)gr0 * DIM + tx * 4] = o0;
        if (gr1 < M) *(float4*)&T[(long)gr1 * DIM + tx * 4] = o1;
    }
}

// ---------------- fallback path (atomic scatter; used only if ws too small) ----------------
__global__ __launch_bounds__(256) void k_init_deg(float* deg, int n) {
    int i = blockIdx.x * 256 + threadIdx.x;
    if (i < n) deg[i] = 1.0f;
}
__global__ __launch_bounds__(256) void k_count_deg(const int* __restrict__ ei, float* deg, int E) {
    int e = blockIdx.x * 256 + threadIdx.x;
    if (e < E) atomAddF(&deg[ei[E + e]], 1.0f);
}
__global__ __launch_bounds__(256) void k_rsqrt(float* deg, int n) {
    int i = blockIdx.x * 256 + threadIdx.x;
    if (i < n) deg[i] = rsqrtf(deg[i]);
}
template<bool BIAS>
__global__ __launch_bounds__(256) void k_self(const float* __restrict__ src,
                                              const float* __restrict__ dinv,
                                              const float* __restrict__ b,
                                              float* __restrict__ out, int n) {
    int g = blockIdx.x * 256 + threadIdx.x;
    int i = g >> 4, c = g & 15;
    if (i >= n) return;
    float di = dinv[i];
    float s = di * di;
    float4 v = *(const float4*)&src[(long)i * DIM + c * 4];
    float4 r = make_float4(v.x * s, v.y * s, v.z * s, v.w * s);
    if (BIAS) {
        float4 bv = *(const float4*)&b[c * 4];
        r.x += bv.x; r.y += bv.y; r.z += bv.z; r.w += bv.w;
    }
    *(float4*)&out[(long)i * DIM + c * 4] = r;
}
__global__ __launch_bounds__(256) void k_edge_agg(const int* __restrict__ ei,
                                                  const float* __restrict__ dinv,
                                                  const float* __restrict__ h,
                                                  float* __restrict__ out, int E) {
    int t = threadIdx.x;
    int e = blockIdx.x * 16 + (t >> 4);
    if (e >= E) return;
    int lane = t & 15;
    int s = ei[e];
    int d = ei[E + e];
    float norm = dinv[s] * dinv[d];
    float4 hv = *(const float4*)&h[(long)s * DIM + lane * 4];
    float* o = &out[(long)d * DIM + lane * 4];
    atomAddF(o + 0, hv.x * norm);
    atomAddF(o + 1, hv.y * norm);
    atomAddF(o + 2, hv.z * norm);
    atomAddF(o + 3, hv.w * norm);
}

extern "C" void kernel_launch(void* const* d_in, const int* in_sizes, int n_in,
                              void* d_out, int out_size, void* d_ws, size_t ws_size,
                              hipStream_t stream) {
    const float* x  = (const float*)d_in[0];
    const int*   ei = (const int*)d_in[1];   // [2,E] int32
    const float* W1 = (const float*)d_in[2];
    const float* b1 = (const float*)d_in[3];
    const float* W2 = (const float*)d_in[4];
    const float* b2 = (const float*)d_in[5];
    float* out = (float*)d_out;

    const int N = in_sizes[0] / DIM;   // 100000
    const int E = in_sizes[1] / 2;     // 1600000

    const int gn   = (N + 255) / 256;
    const int ge   = (E + 255) / 256;
    const int gagg = (N + 15) / 16;
    const int gmlp = (N + 31) / 32;
    const int gbk  = (E + BK_TILE - 1) / BK_TILE;

    // ws layout (256B-aligned bump). pairs aliases buf (pairs dead before MLP writes buf).
    size_t off = 0;
    auto bump = [&](size_t bytes) { size_t o = off; off = (off + bytes + 255) & ~(size_t)255; return o; };
    size_t o_dinv   = bump((size_t)N * 4);
    size_t o_rowptr = bump((size_t)(N + 1) * 4);
    size_t o_counts = bump((size_t)N * 4);
    size_t o_part   = bump(4096 * 4);
    size_t o_gcur   = bump(NB * 4);
    size_t o_col    = bump((size_t)E * 4);
    size_t o_buf    = bump((size_t)N * DIM * 4);   // >= E*8 (25.6MB >= 12.8MB)
    size_t need_csr = off;

    char* ws = (char*)d_ws;

    if (ws_size >= need_csr) {
        float* dinv   = (float*)(ws + o_dinv);
        int*   rowptr = (int*)(ws + o_rowptr);
        int*   counts = (int*)(ws + o_counts);
        int*   part   = (int*)(ws + o_part);
        int*   gcur   = (int*)(ws + o_gcur);
        int*   col    = (int*)(ws + o_col);
        float* buf    = (float*)(ws + o_buf);
        uint2* pairs  = (uint2*)(ws + o_buf);      // alias

        k_zero_i<<<gn, 256, 0, stream>>>(counts, N);
        k_hist<<<ge, 256, 0, stream>>>(ei, counts, E);
        k_scan1<<<gn, 256, 0, stream>>>(counts, rowptr, part, N);
        k_scan2<<<1, 1024, 0, stream>>>(part, gn);
        k_scan3<<<gn, 256, 0, stream>>>(rowptr, part, N, E);
        k_dinv<<<gn, 256, 0, stream>>>(rowptr, dinv, N);
        k_bucket_base<<<1, NB, 0, stream>>>(rowptr, gcur);
        k_bucket<<<gbk, 256, 0, stream>>>(ei, gcur, pairs, E);
        k_scatter_bkt<<<NB, 256, 0, stream>>>(pairs, rowptr, col, N);

        // d_out = Ahat x
        k_agg_csr<false><<<gagg, 256, 0, stream>>>(rowptr, col, dinv, x, nullptr, out, N);
        // buf = relu(d_out @ W1 + b1) @ W2   (overwrites pairs -- dead)
        k_fused_mlp<<<gmlp, 256, 0, stream>>>(out, W1, b1, W2, buf, N);
        // d_out = Ahat buf + b2
        k_agg_csr<true><<<gagg, 256, 0, stream>>>(rowptr, col, dinv, buf, b2, out, N);
    } else {
        // -------- fallback (atomic scatter) --------
        float* dinv = (float*)ws;
        float* buf  = (float*)(ws + 512 * 1024);
        int gl = ((long)N * 16 + 255) / 256;
        int gedge = (E + 15) / 16;

        k_init_deg<<<gn, 256, 0, stream>>>(dinv, N);
        k_count_deg<<<ge, 256, 0, stream>>>(ei, dinv, E);
        k_rsqrt<<<gn, 256, 0, stream>>>(dinv, N);

        k_self<false><<<gl, 256, 0, stream>>>(x, dinv, nullptr, buf, N);
        k_edge_agg<<<gedge, 256, 0, stream>>>(ei, dinv, x, buf, E);
        k_fused_mlp<<<gmlp, 256, 0, stream>>>(buf, W1, b1, W2, buf, N);
        k_self<true><<<gl, 256, 0, stream>>>(buf, dinv, b2, out, N);
        k_edge_agg<<<gedge, 256, 0, stream>>>(ei, dinv, buf, out, E);
    }
}

// Round 7
// 362.694 us; speedup vs baseline: 9.1387x; 1.0440x over previous
//
#include <hip/hip_runtime.h>

// GCN 2-layer: out = Ahat( relu( Ahat(x) W1 + b1 ) W2 ) + b2, Ahat = D^-1/2 (A+I) D^-1/2.
// Ahat(x W1) = (Ahat x) W1 -> aggregate in 64-dim space both times.
// N=100000, E=1.6M, dims 64->128->64.
//
// R6 post-mortem: k_fused_mlp issue-limited (VALUBusy 38%, 2 rows/thread ->
// 16 FMA per ~3 ds_read_b128, LDS pipe ~ VALU pipe). R7: 64-row tile,
// 4 rows x 8 cols per thread (32 FMA/kk vs ~1.25 b128), A/H LDS overlay
// (65KB, still 2 blocks/CU). agg edge loop unroll x4.

#define DIM 64
#define NB 256          // dst-range buckets
#define SPAN 391        // ceil(100000/256); NB*SPAN >= N
#define BK_TILE 4096
#define BK_PER 16       // edges per thread in k_bucket

__device__ __forceinline__ void atomAddF(float* p, float v) {
    unsafeAtomicAdd(p, v);
}

// ---------------- CSR build ----------------
__global__ __launch_bounds__(256) void k_zero_i(int* p, int n) {
    int i = blockIdx.x * 256 + threadIdx.x;
    if (i < n) p[i] = 0;
}
__global__ __launch_bounds__(256) void k_hist(const int* __restrict__ ei, int* counts, int E) {
    int e = blockIdx.x * 256 + threadIdx.x;
    if (e < E) atomicAdd(&counts[ei[E + e]], 1);   // in-degree of dst
}
__global__ __launch_bounds__(256) void k_scan1(const int* __restrict__ counts,
                                               int* __restrict__ row_ptr,
                                               int* __restrict__ partials, int n) {
    __shared__ int s[256];
    int tid = threadIdx.x;
    int i = blockIdx.x * 256 + tid;
    int v = (i < n) ? counts[i] : 0;
    s[tid] = v; __syncthreads();
    for (int off = 1; off < 256; off <<= 1) {
        int t = (tid >= off) ? s[tid - off] : 0;
        __syncthreads();
        s[tid] += t;
        __syncthreads();
    }
    if (i < n) row_ptr[i] = s[tid] - v;            // exclusive
    if (tid == 255) partials[blockIdx.x] = s[255]; // inclusive total
}
__global__ __launch_bounds__(1024) void k_scan2(int* partials, int nb) {
    __shared__ int s[1024];
    int tid = threadIdx.x;
    int v = (tid < nb) ? partials[tid] : 0;
    s[tid] = v; __syncthreads();
    for (int off = 1; off < 1024; off <<= 1) {
        int t = (tid >= off) ? s[tid - off] : 0;
        __syncthreads();
        s[tid] += t;
        __syncthreads();
    }
    if (tid < nb) partials[tid] = s[tid] - v;
}
__global__ __launch_bounds__(256) void k_scan3(int* __restrict__ row_ptr,
                                               const int* __restrict__ partials, int n, int E) {
    int i = blockIdx.x * 256 + threadIdx.x;
    if (i < n) row_ptr[i] += partials[blockIdx.x];
    if (i == 0) row_ptr[n] = E;
}
__global__ __launch_bounds__(256) void k_dinv(const int* __restrict__ row_ptr,
                                              float* __restrict__ dinv, int n) {
    int i = blockIdx.x * 256 + threadIdx.x;
    if (i < n) dinv[i] = rsqrtf(1.0f + (float)(row_ptr[i + 1] - row_ptr[i]));  // +1 self-loop
}
__global__ __launch_bounds__(NB) void k_bucket_base(const int* __restrict__ row_ptr,
                                                    int* __restrict__ gcur) {
    int b = threadIdx.x;
    gcur[b] = row_ptr[b * SPAN];
}

// Phase A: tile multisplit -> bucket-grouped (src,dst) pairs, coalesced writes.
__global__ __launch_bounds__(256) void k_bucket(const int* __restrict__ ei,
                                                int* __restrict__ gcur,
                                                uint2* __restrict__ pairs, int E) {
    __shared__ int scn[NB];
    __shared__ int run[NB];
    __shared__ int lbase[NB];
    __shared__ int gbase[NB];
    __shared__ uint2 stage[BK_TILE];
    __shared__ unsigned char bkt[BK_TILE];
    const int tid = threadIdx.x;
    const int base = blockIdx.x * BK_TILE;

    scn[tid] = 0;
    __syncthreads();

    int sv[BK_PER], dv[BK_PER], bv[BK_PER];
    #pragma unroll
    for (int j = 0; j < BK_PER; ++j) {
        int e = base + j * 256 + tid;
        if (e < E) {
            sv[j] = ei[e];
            dv[j] = ei[E + e];
            bv[j] = (int)((unsigned)dv[j] / (unsigned)SPAN);
            atomicAdd(&scn[bv[j]], 1);
        } else bv[j] = -1;
    }
    __syncthreads();
    int c = scn[tid];
    for (int off = 1; off < 256; off <<= 1) {
        int t = (tid >= off) ? scn[tid - off] : 0;
        __syncthreads();
        scn[tid] += t;
        __syncthreads();
    }
    int ex = scn[tid] - c;
    lbase[tid] = ex;
    run[tid] = ex;
    if (c > 0) gbase[tid] = atomicAdd(&gcur[tid], c);
    __syncthreads();

    #pragma unroll
    for (int j = 0; j < BK_PER; ++j) {
        if (bv[j] >= 0) {
            int p = atomicAdd(&run[bv[j]], 1);
            stage[p] = make_uint2((unsigned)sv[j], (unsigned)dv[j]);
            bkt[p] = (unsigned char)bv[j];
        }
    }
    __syncthreads();

    int total = min(BK_TILE, E - base);
    for (int i = tid; i < total; i += 256) {
        int bb = bkt[i];
        pairs[gbase[bb] + (i - lbase[bb])] = stage[i];
    }
}

// Phase B: one block per bucket; single-XCD col window, LDS cursors.
__global__ __launch_bounds__(256) void k_scatter_bkt(const uint2* __restrict__ pairs,
                                                     const int* __restrict__ row_ptr,
                                                     int* __restrict__ col, int N) {
    __shared__ int lcur[SPAN];
    const int tid = threadIdx.x;
    const int b = blockIdx.x;
    const int lo = b * SPAN;
    const int hi = min(lo + SPAN, N);
    const int nn = hi - lo;
    for (int i = tid; i < nn; i += 256) lcur[i] = row_ptr[lo + i];
    __syncthreads();
    const int p0 = row_ptr[lo];
    const int p1 = row_ptr[hi];
    for (int i = p0 + tid; i < p1; i += 256) {
        uint2 pr = pairs[i];
        int pos = atomicAdd(&lcur[(int)pr.y - lo], 1);
        col[pos] = (int)pr.x;
    }
}

// ---------------- CSR aggregation (atomic-free, unroll x4) ----------------
// out[d] = dinv[d] * ( dinv[d]*h[d] + sum_{s in N(d)} dinv[s]*h[s] ) [+ b]
template<bool BIAS>
__global__ __launch_bounds__(256) void k_agg_csr(const int* __restrict__ row_ptr,
                                                 const int* __restrict__ col,
                                                 const float* __restrict__ dinv,
                                                 const float* __restrict__ h,
                                                 const float* __restrict__ b,
                                                 float* __restrict__ out, int n) {
    int g = blockIdx.x * 16 + (threadIdx.x >> 4);
    if (g >= n) return;
    int lane = threadIdx.x & 15;
    const float4* h4 = (const float4*)h;
    float di = dinv[g];
    float4 hv = h4[(long)g * 16 + lane];
    float4 a0 = make_float4(hv.x * di, hv.y * di, hv.z * di, hv.w * di);  // self term
    float4 a1 = make_float4(0.f, 0.f, 0.f, 0.f), a2 = a1, a3 = a1;
    int e0 = row_ptr[g], e1 = row_ptr[g + 1];
    int e = e0;
    for (; e + 4 <= e1; e += 4) {
        int s0 = col[e], s1 = col[e + 1], s2 = col[e + 2], s3 = col[e + 3];
        float d0 = dinv[s0], d1 = dinv[s1], d2 = dinv[s2], d3 = dinv[s3];
        float4 v0 = h4[(long)s0 * 16 + lane];
        float4 v1 = h4[(long)s1 * 16 + lane];
        float4 v2 = h4[(long)s2 * 16 + lane];
        float4 v3 = h4[(long)s3 * 16 + lane];
        a0.x += d0 * v0.x; a0.y += d0 * v0.y; a0.z += d0 * v0.z; a0.w += d0 * v0.w;
        a1.x += d1 * v1.x; a1.y += d1 * v1.y; a1.z += d1 * v1.z; a1.w += d1 * v1.w;
        a2.x += d2 * v2.x; a2.y += d2 * v2.y; a2.z += d2 * v2.z; a2.w += d2 * v2.w;
        a3.x += d3 * v3.x; a3.y += d3 * v3.y; a3.z += d3 * v3.z; a3.w += d3 * v3.w;
    }
    for (; e < e1; ++e) {
        int s0 = col[e];
        float d0 = dinv[s0];
        float4 v0 = h4[(long)s0 * 16 + lane];
        a0.x += d0 * v0.x; a0.y += d0 * v0.y; a0.z += d0 * v0.z; a0.w += d0 * v0.w;
    }
    a0.x = (a0.x + a1.x + a2.x + a3.x) * di;
    a0.y = (a0.y + a1.y + a2.y + a3.y) * di;
    a0.z = (a0.z + a1.z + a2.z + a3.z) * di;
    a0.w = (a0.w + a1.w + a2.w + a3.w) * di;
    if (BIAS) {
        float4 bv = ((const float4*)b)[lane];
        a0.x += bv.x; a0.y += bv.y; a0.z += bv.z; a0.w += bv.w;
    }
    ((float4*)out)[(long)g * 16 + lane] = a0;
}

// ---------------- fused MLP v3: T = relu(G @ W1 + b1) @ W2 ----------------
// 64-row tile, 256 threads, 4 rows x 8 cols per thread (stage 1).
// LDS: W (32KB, W1 then W2) + HA overlay (A as [64][68], then H as [64][132]).
__global__ __launch_bounds__(256) void k_fused_mlp(const float* __restrict__ G,  // [N,64]
                                                   const float* __restrict__ W1, // [64,128]
                                                   const float* __restrict__ b1, // [128]
                                                   const float* __restrict__ W2, // [128,64]
                                                   float* __restrict__ T,        // [N,64]
                                                   int M) {
    __shared__ float Ws[64 * 128];   // 32 KB
    __shared__ float HA[64 * 132];   // 33 KB: A tile (stride 68), then H tile (stride 132)
    const int tid = threadIdx.x;
    const int row0 = blockIdx.x * 64;
    const int ty = tid >> 4;        // 0..15 -> rows ty*4 .. ty*4+3
    const int tx = tid & 15;        // 0..15

    // stage A tile (64x64): 1024 float4, 4/thread. stride 68 (272B, 16B-aligned)
    #pragma unroll
    for (int l = 0; l < 4; ++l) {
        int idx = l * 256 + tid;
        int r = idx >> 4, cv = idx & 15;
        int gr = row0 + r;
        float4 v = make_float4(0.f, 0.f, 0.f, 0.f);
        if (gr < M) v = *(const float4*)&G[(long)gr * DIM + cv * 4];
        *(float4*)&HA[r * 68 + cv * 4] = v;
    }
    // stage W1 (8192 floats): 8 float4/thread
    #pragma unroll
    for (int l = 0; l < 8; ++l) {
        int idx = (l * 256 + tid) * 4;
        *(float4*)&Ws[idx] = *(const float4*)&W1[idx];
    }
    __syncthreads();

    // stage 1: h(64x128) = A @ W1. rows ty*4+i, cols tx*8..+7
    float4 accA[4], accB[4];
    #pragma unroll
    for (int i = 0; i < 4; ++i) {
        accA[i] = make_float4(0.f, 0.f, 0.f, 0.f);
        accB[i] = make_float4(0.f, 0.f, 0.f, 0.f);
    }
    for (int k4 = 0; k4 < 64; k4 += 4) {
        float4 a[4];
        #pragma unroll
        for (int i = 0; i < 4; ++i) a[i] = *(const float4*)&HA[(ty * 4 + i) * 68 + k4];
        #pragma unroll
        for (int kk = 0; kk < 4; ++kk) {
            const float* wr = &Ws[(k4 + kk) * 128 + tx * 8];
            float4 wA = *(const float4*)wr;
            float4 wB = *(const float4*)(wr + 4);
            #pragma unroll
            for (int i = 0; i < 4; ++i) {
                float ak = (&a[i].x)[kk];
                accA[i].x += ak * wA.x; accA[i].y += ak * wA.y;
                accA[i].z += ak * wA.z; accA[i].w += ak * wA.w;
                accB[i].x += ak * wB.x; accB[i].y += ak * wB.y;
                accB[i].z += ak * wB.z; accB[i].w += ak * wB.w;
            }
        }
    }
    __syncthreads();   // all A reads and all W1 reads done

    // write H = relu(acc + b1) into HA (stride 132; 528B row, 16B-aligned);
    // reload W region with W2.
    {
        float4 bA = *(const float4*)&b1[tx * 8];
        float4 bB = *(const float4*)&b1[tx * 8 + 4];
        #pragma unroll
        for (int i = 0; i < 4; ++i) {
            float4 hA = make_float4(fmaxf(accA[i].x + bA.x, 0.f), fmaxf(accA[i].y + bA.y, 0.f),
                                    fmaxf(accA[i].z + bA.z, 0.f), fmaxf(accA[i].w + bA.w, 0.f));
            float4 hB = make_float4(fmaxf(accB[i].x + bB.x, 0.f), fmaxf(accB[i].y + bB.y, 0.f),
                                    fmaxf(accB[i].z + bB.z, 0.f), fmaxf(accB[i].w + bB.w, 0.f));
            *(float4*)&HA[(ty * 4 + i) * 132 + tx * 8 + 0] = hA;
            *(float4*)&HA[(ty * 4 + i) * 132 + tx * 8 + 4] = hB;
        }
    }
    #pragma unroll
    for (int l = 0; l < 8; ++l) {
        int idx = (l * 256 + tid) * 4;
        *(float4*)&Ws[idx] = *(const float4*)&W2[idx];
    }
    __syncthreads();

    // stage 2: t(64x64) = H @ W2. rows ty*4+i, cols tx*4..+3
    float4 o[4];
    #pragma unroll
    for (int i = 0; i < 4; ++i) o[i] = make_float4(0.f, 0.f, 0.f, 0.f);
    for (int k4 = 0; k4 < 128; k4 += 4) {
        float4 a[4];
        #pragma unroll
        for (int i = 0; i < 4; ++i) a[i] = *(const float4*)&HA[(ty * 4 + i) * 132 + k4];
        #pragma unroll
        for (int kk = 0; kk < 4; ++kk) {
            float4 w = *(const float4*)&Ws[(k4 + kk) * 64 + tx * 4];
            #pragma unroll
            for (int i = 0; i < 4; ++i) {
                float ak = (&a[i].x)[kk];
                o[i].x += ak * w.x; o[i].y += ak * w.y;
                o[i].z += ak * w.z; o[i].w += ak * w.w;
            }
        }
    }
    #pragma unroll
    for (int i = 0; i < 4; ++i) {
        int gr = row0 + ty * 4 + i;
        if (gr < M) *(float4*)&T[(long)gr * DIM + tx * 4] = o[i];
    }
}

// ---------------- fallback path (atomic scatter; used only if ws too small) ----------------
__global__ __launch_bounds__(256) void k_init_deg(float* deg, int n) {
    int i = blockIdx.x * 256 + threadIdx.x;
    if (i < n) deg[i] = 1.0f;
}
__global__ __launch_bounds__(256) void k_count_deg(const int* __restrict__ ei, float* deg, int E) {
    int e = blockIdx.x * 256 + threadIdx.x;
    if (e < E) atomAddF(&deg[ei[E + e]], 1.0f);
}
__global__ __launch_bounds__(256) void k_rsqrt(float* deg, int n) {
    int i = blockIdx.x * 256 + threadIdx.x;
    if (i < n) deg[i] = rsqrtf(deg[i]);
}
template<bool BIAS>
__global__ __launch_bounds__(256) void k_self(const float* __restrict__ src,
                                              const float* __restrict__ dinv,
                                              const float* __restrict__ b,
                                              float* __restrict__ out, int n) {
    int g = blockIdx.x * 256 + threadIdx.x;
    int i = g >> 4, c = g & 15;
    if (i >= n) return;
    float di = dinv[i];
    float s = di * di;
    float4 v = *(const float4*)&src[(long)i * DIM + c * 4];
    float4 r = make_float4(v.x * s, v.y * s, v.z * s, v.w * s);
    if (BIAS) {
        float4 bv = *(const float4*)&b[c * 4];
        r.x += bv.x; r.y += bv.y; r.z += bv.z; r.w += bv.w;
    }
    *(float4*)&out[(long)i * DIM + c * 4] = r;
}
__global__ __launch_bounds__(256) void k_edge_agg(const int* __restrict__ ei,
                                                  const float* __restrict__ dinv,
                                                  const float* __restrict__ h,
                                                  float* __restrict__ out, int E) {
    int t = threadIdx.x;
    int e = blockIdx.x * 16 + (t >> 4);
    if (e >= E) return;
    int lane = t & 15;
    int s = ei[e];
    int d = ei[E + e];
    float norm = dinv[s] * dinv[d];
    float4 hv = *(const float4*)&h[(long)s * DIM + lane * 4];
    float* o = &out[(long)d * DIM + lane * 4];
    atomAddF(o + 0, hv.x * norm);
    atomAddF(o + 1, hv.y * norm);
    atomAddF(o + 2, hv.z * norm);
    atomAddF(o + 3, hv.w * norm);
}

extern "C" void kernel_launch(void* const* d_in, const int* in_sizes, int n_in,
                              void* d_out, int out_size, void* d_ws, size_t ws_size,
                              hipStream_t stream) {
    const float* x  = (const float*)d_in[0];
    const int*   ei = (const int*)d_in[1];   // [2,E] int32
    const float* W1 = (const float*)d_in[2];
    const float* b1 = (const float*)d_in[3];
    const float* W2 = (const float*)d_in[4];
    const float* b2 = (const float*)d_in[5];
    float* out = (float*)d_out;

    const int N = in_sizes[0] / DIM;   // 100000
    const int E = in_sizes[1] / 2;     // 1600000

    const int gn   = (N + 255) / 256;
    const int ge   = (E + 255) / 256;
    const int gagg = (N + 15) / 16;
    const int gmlp = (N + 63) / 64;
    const int gbk  = (E + BK_TILE - 1) / BK_TILE;

    // ws layout (256B-aligned bump). pairs aliases buf (pairs dead before MLP writes buf).
    size_t off = 0;
    auto bump = [&](size_t bytes) { size_t o = off; off = (off + bytes + 255) & ~(size_t)255; return o; };
    size_t o_dinv   = bump((size_t)N * 4);
    size_t o_rowptr = bump((size_t)(N + 1) * 4);
    size_t o_counts = bump((size_t)N * 4);
    size_t o_part   = bump(4096 * 4);
    size_t o_gcur   = bump(NB * 4);
    size_t o_col    = bump((size_t)E * 4);
    size_t o_buf    = bump((size_t)N * DIM * 4);   // >= E*8 (25.6MB >= 12.8MB)
    size_t need_csr = off;

    char* ws = (char*)d_ws;

    if (ws_size >= need_csr) {
        float* dinv   = (float*)(ws + o_dinv);
        int*   rowptr = (int*)(ws + o_rowptr);
        int*   counts = (int*)(ws + o_counts);
        int*   part   = (int*)(ws + o_part);
        int*   gcur   = (int*)(ws + o_gcur);
        int*   col    = (int*)(ws + o_col);
        float* buf    = (float*)(ws + o_buf);
        uint2* pairs  = (uint2*)(ws + o_buf);      // alias

        k_zero_i<<<gn, 256, 0, stream>>>(counts, N);
        k_hist<<<ge, 256, 0, stream>>>(ei, counts, E);
        k_scan1<<<gn, 256, 0, stream>>>(counts, rowptr, part, N);
        k_scan2<<<1, 1024, 0, stream>>>(part, gn);
        k_scan3<<<gn, 256, 0, stream>>>(rowptr, part, N, E);
        k_dinv<<<gn, 256, 0, stream>>>(rowptr, dinv, N);
        k_bucket_base<<<1, NB, 0, stream>>>(rowptr, gcur);
        k_bucket<<<gbk, 256, 0, stream>>>(ei, gcur, pairs, E);
        k_scatter_bkt<<<NB, 256, 0, stream>>>(pairs, rowptr, col, N);

        // d_out = Ahat x
        k_agg_csr<false><<<gagg, 256, 0, stream>>>(rowptr, col, dinv, x, nullptr, out, N);
        // buf = relu(d_out @ W1 + b1) @ W2   (overwrites pairs -- dead)
        k_fused_mlp<<<gmlp, 256, 0, stream>>>(out, W1, b1, W2, buf, N);
        // d_out = Ahat buf + b2
        k_agg_csr<true><<<gagg, 256, 0, stream>>>(rowptr, col, dinv, buf, b2, out, N);
    } else {
        // -------- fallback (atomic scatter) --------
        float* dinv = (float*)ws;
        float* buf  = (float*)(ws + 512 * 1024);
        int gl = ((long)N * 16 + 255) / 256;
        int gedge = (E + 15) / 16;

        k_init_deg<<<gn, 256, 0, stream>>>(dinv, N);
        k_count_deg<<<ge, 256, 0, stream>>>(ei, dinv, E);
        k_rsqrt<<<gn, 256, 0, stream>>>(dinv, N);

        k_self<false><<<gl, 256, 0, stream>>>(x, dinv, nullptr, buf, N);
        k_edge_agg<<<gedge, 256, 0, stream>>>(ei, dinv, x, buf, E);
        k_fused_mlp<<<(N + 63) / 64, 256, 0, stream>>>(buf, W1, b1, W2, buf, N);
        k_self<true><<<gl, 256, 0, stream>>>(buf, dinv, b2, out, N);
        k_edge_agg<<<gedge, 256, 0, stream>>>(ei, dinv, buf, out, E);
    }
}

// Round 8
// 304.427 us; speedup vs baseline: 10.8879x; 1.1914x over previous
//
#include <hip/hip_runtime.h>

// GCN 2-layer: out = Ahat( relu( Ahat(x) W1 + b1 ) W2 ) + b2, Ahat = D^-1/2 (A+I) D^-1/2.
// Ahat(x W1) = (Ahat x) W1 -> aggregate in 64-dim space both times.
// N=100000, E=1.6M, dims 64->128->64.
//
// R7 post-mortem: k_hist (1.6M global atomics on 400KB counts) was #1 at 66us,
// WRITE_SIZE 50MB of cross-XCD line thrash; the whole N-wide hist+scan chain
// exists only to size buckets/rows. R8: 256-bin LDS hist (bucket totals only),
// bucket-local 391-node hist+scan+scatter in k_finish. Deletes 7 kernels.

#define DIM 64
#define NB 256          // dst-range buckets
#define SPAN 391        // ceil(100000/256); NB*SPAN >= N
#define BK_TILE 4096
#define BK_PER 16       // edges per thread in k_bucket

__device__ __forceinline__ void atomAddF(float* p, float v) {
    unsafeAtomicAdd(p, v);
}

// ---------------- bucket totals ----------------
__global__ __launch_bounds__(256) void k_zero256(int* p) {
    p[threadIdx.x] = 0;
}
// LDS-privatized 256-bin histogram of dst/SPAN
__global__ __launch_bounds__(256) void k_hist256(const int* __restrict__ ei,
                                                 int* __restrict__ bucketCnt, int E) {
    __shared__ int h[NB];
    const int tid = threadIdx.x;
    h[tid] = 0;
    __syncthreads();
    const int base = blockIdx.x * BK_TILE;
    #pragma unroll
    for (int j = 0; j < BK_TILE; j += 256) {
        int e = base + j + tid;
        if (e < E) atomicAdd(&h[(unsigned)ei[E + e] / (unsigned)SPAN], 1);
    }
    __syncthreads();
    if (h[tid]) atomicAdd(&bucketCnt[tid], h[tid]);
}
// one block: exclusive scan of 256 totals -> bucketBase[0..256]; seed gcur
__global__ __launch_bounds__(256) void k_scan_b(const int* __restrict__ bucketCnt,
                                                int* __restrict__ bucketBase,
                                                int* __restrict__ gcur) {
    __shared__ int s[NB];
    const int tid = threadIdx.x;
    int v = bucketCnt[tid];
    s[tid] = v;
    __syncthreads();
    for (int off = 1; off < NB; off <<= 1) {
        int t = (tid >= off) ? s[tid - off] : 0;
        __syncthreads();
        s[tid] += t;
        __syncthreads();
    }
    int ex = s[tid] - v;
    bucketBase[tid] = ex;
    gcur[tid] = ex;
    if (tid == NB - 1) bucketBase[NB] = s[NB - 1];
}

// Phase A: tile multisplit -> bucket-grouped (src,dst) pairs, coalesced writes.
__global__ __launch_bounds__(256) void k_bucket(const int* __restrict__ ei,
                                                int* __restrict__ gcur,
                                                uint2* __restrict__ pairs, int E) {
    __shared__ int scn[NB];
    __shared__ int run[NB];
    __shared__ int lbase[NB];
    __shared__ int gbase[NB];
    __shared__ uint2 stage[BK_TILE];
    __shared__ unsigned char bkt[BK_TILE];
    const int tid = threadIdx.x;
    const int base = blockIdx.x * BK_TILE;

    scn[tid] = 0;
    __syncthreads();

    int sv[BK_PER], dv[BK_PER], bv[BK_PER];
    #pragma unroll
    for (int j = 0; j < BK_PER; ++j) {
        int e = base + j * 256 + tid;
        if (e < E) {
            sv[j] = ei[e];
            dv[j] = ei[E + e];
            bv[j] = (int)((unsigned)dv[j] / (unsigned)SPAN);
            atomicAdd(&scn[bv[j]], 1);
        } else bv[j] = -1;
    }
    __syncthreads();
    int c = scn[tid];
    for (int off = 1; off < 256; off <<= 1) {
        int t = (tid >= off) ? scn[tid - off] : 0;
        __syncthreads();
        scn[tid] += t;
        __syncthreads();
    }
    int ex = scn[tid] - c;
    lbase[tid] = ex;
    run[tid] = ex;
    if (c > 0) gbase[tid] = atomicAdd(&gcur[tid], c);
    __syncthreads();

    #pragma unroll
    for (int j = 0; j < BK_PER; ++j) {
        if (bv[j] >= 0) {
            int p = atomicAdd(&run[bv[j]], 1);
            stage[p] = make_uint2((unsigned)sv[j], (unsigned)dv[j]);
            bkt[p] = (unsigned char)bv[j];
        }
    }
    __syncthreads();

    int total = min(BK_TILE, E - base);
    for (int i = tid; i < total; i += 256) {
        int bb = bkt[i];
        pairs[gbase[bb] + (i - lbase[bb])] = stage[i];
    }
}

// Phase B: one block per bucket. Local node hist -> scan -> row_ptr/dinv/col.
// All col/row_ptr writes for the bucket window come from one CU (full lines).
__global__ __launch_bounds__(256) void k_finish(const uint2* __restrict__ pairs,
                                                const int* __restrict__ bucketBase,
                                                int* __restrict__ row_ptr,
                                                float* __restrict__ dinv,
                                                int* __restrict__ col, int N) {
    __shared__ int lh[512];
    __shared__ int sa[512];
    __shared__ int sb[512];
    __shared__ int lcur[SPAN];
    const int tid = threadIdx.x;
    const int b = blockIdx.x;
    const int lo = b * SPAN;
    const int hi = min(lo + SPAN, N);
    const int nn = hi - lo;
    const int p0 = bucketBase[b];
    const int p1 = bucketBase[b + 1];

    for (int i = tid; i < 512; i += 256) lh[i] = 0;
    __syncthreads();
    for (int e = p0 + tid; e < p1; e += 256)
        atomicAdd(&lh[(int)pairs[e].y - lo], 1);
    __syncthreads();
    // Hillis-Steele inclusive scan over 512 (double buffer)
    int* cur = sa;
    int* nxt = sb;
    for (int i = tid; i < 512; i += 256) sa[i] = lh[i];
    __syncthreads();
    for (int off = 1; off < 512; off <<= 1) {
        for (int i = tid; i < 512; i += 256)
            nxt[i] = cur[i] + ((i >= off) ? cur[i - off] : 0);
        __syncthreads();
        int* t = cur; cur = nxt; nxt = t;
    }
    for (int i = tid; i < nn; i += 256) {
        int cnt  = lh[i];
        int base = p0 + cur[i] - cnt;      // p0 + exclusive prefix
        row_ptr[lo + i] = base;
        lcur[i] = base;
        dinv[lo + i] = rsqrtf(1.0f + (float)cnt);   // +1 self-loop
    }
    if (b == NB - 1 && tid == 0) row_ptr[N] = p1;
    __syncthreads();
    for (int e = p0 + tid; e < p1; e += 256) {
        uint2 pr = pairs[e];
        int pos = atomicAdd(&lcur[(int)pr.y - lo], 1);
        col[pos] = (int)pr.x;
    }
}

// ---------------- CSR aggregation (atomic-free, unroll x4) ----------------
// out[d] = dinv[d] * ( dinv[d]*h[d] + sum_{s in N(d)} dinv[s]*h[s] ) [+ b]
template<bool BIAS>
__global__ __launch_bounds__(256) void k_agg_csr(const int* __restrict__ row_ptr,
                                                 const int* __restrict__ col,
                                                 const float* __restrict__ dinv,
                                                 const float* __restrict__ h,
                                                 const float* __restrict__ b,
                                                 float* __restrict__ out, int n) {
    int g = blockIdx.x * 16 + (threadIdx.x >> 4);
    if (g >= n) return;
    int lane = threadIdx.x & 15;
    const float4* h4 = (const float4*)h;
    float di = dinv[g];
    float4 hv = h4[(long)g * 16 + lane];
    float4 a0 = make_float4(hv.x * di, hv.y * di, hv.z * di, hv.w * di);  // self term
    float4 a1 = make_float4(0.f, 0.f, 0.f, 0.f), a2 = a1, a3 = a1;
    int e0 = row_ptr[g], e1 = row_ptr[g + 1];
    int e = e0;
    for (; e + 4 <= e1; e += 4) {
        int s0 = col[e], s1 = col[e + 1], s2 = col[e + 2], s3 = col[e + 3];
        float d0 = dinv[s0], d1 = dinv[s1], d2 = dinv[s2], d3 = dinv[s3];
        float4 v0 = h4[(long)s0 * 16 + lane];
        float4 v1 = h4[(long)s1 * 16 + lane];
        float4 v2 = h4[(long)s2 * 16 + lane];
        float4 v3 = h4[(long)s3 * 16 + lane];
        a0.x += d0 * v0.x; a0.y += d0 * v0.y; a0.z += d0 * v0.z; a0.w += d0 * v0.w;
        a1.x += d1 * v1.x; a1.y += d1 * v1.y; a1.z += d1 * v1.z; a1.w += d1 * v1.w;
        a2.x += d2 * v2.x; a2.y += d2 * v2.y; a2.z += d2 * v2.z; a2.w += d2 * v2.w;
        a3.x += d3 * v3.x; a3.y += d3 * v3.y; a3.z += d3 * v3.z; a3.w += d3 * v3.w;
    }
    for (; e < e1; ++e) {
        int s0 = col[e];
        float d0 = dinv[s0];
        float4 v0 = h4[(long)s0 * 16 + lane];
        a0.x += d0 * v0.x; a0.y += d0 * v0.y; a0.z += d0 * v0.z; a0.w += d0 * v0.w;
    }
    a0.x = (a0.x + a1.x + a2.x + a3.x) * di;
    a0.y = (a0.y + a1.y + a2.y + a3.y) * di;
    a0.z = (a0.z + a1.z + a2.z + a3.z) * di;
    a0.w = (a0.w + a1.w + a2.w + a3.w) * di;
    if (BIAS) {
        float4 bv = ((const float4*)b)[lane];
        a0.x += bv.x; a0.y += bv.y; a0.z += bv.z; a0.w += bv.w;
    }
    ((float4*)out)[(long)g * 16 + lane] = a0;
}

// ---------------- fused MLP: T = relu(G @ W1 + b1) @ W2 ----------------
// 64-row tile, 256 threads, 4 rows x 8 cols per thread (stage 1).
__global__ __launch_bounds__(256) void k_fused_mlp(const float* __restrict__ G,  // [N,64]
                                                   const float* __restrict__ W1, // [64,128]
                                                   const float* __restrict__ b1, // [128]
                                                   const float* __restrict__ W2, // [128,64]
                                                   float* __restrict__ T,        // [N,64]
                                                   int M) {
    __shared__ float Ws[64 * 128];   // 32 KB
    __shared__ float HA[64 * 132];   // 33 KB: A tile (stride 68), then H tile (stride 132)
    const int tid = threadIdx.x;
    const int row0 = blockIdx.x * 64;
    const int ty = tid >> 4;
    const int tx = tid & 15;

    #pragma unroll
    for (int l = 0; l < 4; ++l) {
        int idx = l * 256 + tid;
        int r = idx >> 4, cv = idx & 15;
        int gr = row0 + r;
        float4 v = make_float4(0.f, 0.f, 0.f, 0.f);
        if (gr < M) v = *(const float4*)&G[(long)gr * DIM + cv * 4];
        *(float4*)&HA[r * 68 + cv * 4] = v;
    }
    #pragma unroll
    for (int l = 0; l < 8; ++l) {
        int idx = (l * 256 + tid) * 4;
        *(float4*)&Ws[idx] = *(const float4*)&W1[idx];
    }
    __syncthreads();

    float4 accA[4], accB[4];
    #pragma unroll
    for (int i = 0; i < 4; ++i) {
        accA[i] = make_float4(0.f, 0.f, 0.f, 0.f);
        accB[i] = make_float4(0.f, 0.f, 0.f, 0.f);
    }
    for (int k4 = 0; k4 < 64; k4 += 4) {
        float4 a[4];
        #pragma unroll
        for (int i = 0; i < 4; ++i) a[i] = *(const float4*)&HA[(ty * 4 + i) * 68 + k4];
        #pragma unroll
        for (int kk = 0; kk < 4; ++kk) {
            const float* wr = &Ws[(k4 + kk) * 128 + tx * 8];
            float4 wA = *(const float4*)wr;
            float4 wB = *(const float4*)(wr + 4);
            #pragma unroll
            for (int i = 0; i < 4; ++i) {
                float ak = (&a[i].x)[kk];
                accA[i].x += ak * wA.x; accA[i].y += ak * wA.y;
                accA[i].z += ak * wA.z; accA[i].w += ak * wA.w;
                accB[i].x += ak * wB.x; accB[i].y += ak * wB.y;
                accB[i].z += ak * wB.z; accB[i].w += ak * wB.w;
            }
        }
    }
    __syncthreads();

    {
        float4 bA = *(const float4*)&b1[tx * 8];
        float4 bB = *(const float4*)&b1[tx * 8 + 4];
        #pragma unroll
        for (int i = 0; i < 4; ++i) {
            float4 hA = make_float4(fmaxf(accA[i].x + bA.x, 0.f), fmaxf(accA[i].y + bA.y, 0.f),
                                    fmaxf(accA[i].z + bA.z, 0.f), fmaxf(accA[i].w + bA.w, 0.f));
            float4 hB = make_float4(fmaxf(accB[i].x + bB.x, 0.f), fmaxf(accB[i].y + bB.y, 0.f),
                                    fmaxf(accB[i].z + bB.z, 0.f), fmaxf(accB[i].w + bB.w, 0.f));
            *(float4*)&HA[(ty * 4 + i) * 132 + tx * 8 + 0] = hA;
            *(float4*)&HA[(ty * 4 + i) * 132 + tx * 8 + 4] = hB;
        }
    }
    #pragma unroll
    for (int l = 0; l < 8; ++l) {
        int idx = (l * 256 + tid) * 4;
        *(float4*)&Ws[idx] = *(const float4*)&W2[idx];
    }
    __syncthreads();

    float4 o[4];
    #pragma unroll
    for (int i = 0; i < 4; ++i) o[i] = make_float4(0.f, 0.f, 0.f, 0.f);
    for (int k4 = 0; k4 < 128; k4 += 4) {
        float4 a[4];
        #pragma unroll
        for (int i = 0; i < 4; ++i) a[i] = *(const float4*)&HA[(ty * 4 + i) * 132 + k4];
        #pragma unroll
        for (int kk = 0; kk < 4; ++kk) {
            float4 w = *(const float4*)&Ws[(k4 + kk) * 64 + tx * 4];
            #pragma unroll
            for (int i = 0; i < 4; ++i) {
                float ak = (&a[i].x)[kk];
                o[i].x += ak * w.x; o[i].y += ak * w.y;
                o[i].z += ak * w.z; o[i].w += ak * w.w;
            }
        }
    }
    #pragma unroll
    for (int i = 0; i < 4; ++i) {
        int gr = row0 + ty * 4 + i;
        if (gr < M) *(float4*)&T[(long)gr * DIM + tx * 4] = o[i];
    }
}

// ---------------- fallback path (atomic scatter; used only if ws too small) ----------------
__global__ __launch_bounds__(256) void k_init_deg(float* deg, int n) {
    int i = blockIdx.x * 256 + threadIdx.x;
    if (i < n) deg[i] = 1.0f;
}
__global__ __launch_bounds__(256) void k_count_deg(const int* __restrict__ ei, float* deg, int E) {
    int e = blockIdx.x * 256 + threadIdx.x;
    if (e < E) atomAddF(&deg[ei[E + e]], 1.0f);
}
__global__ __launch_bounds__(256) void k_rsqrt(float* deg, int n) {
    int i = blockIdx.x * 256 + threadIdx.x;
    if (i < n) deg[i] = rsqrtf(deg[i]);
}
template<bool BIAS>
__global__ __launch_bounds__(256) void k_self(const float* __restrict__ src,
                                              const float* __restrict__ dinv,
                                              const float* __restrict__ b,
                                              float* __restrict__ out, int n) {
    int g = blockIdx.x * 256 + threadIdx.x;
    int i = g >> 4, c = g & 15;
    if (i >= n) return;
    float di = dinv[i];
    float s = di * di;
    float4 v = *(const float4*)&src[(long)i * DIM + c * 4];
    float4 r = make_float4(v.x * s, v.y * s, v.z * s, v.w * s);
    if (BIAS) {
        float4 bv = *(const float4*)&b[c * 4];
        r.x += bv.x; r.y += bv.y; r.z += bv.z; r.w += bv.w;
    }
    *(float4*)&out[(long)i * DIM + c * 4] = r;
}
__global__ __launch_bounds__(256) void k_edge_agg(const int* __restrict__ ei,
                                                  const float* __restrict__ dinv,
                                                  const float* __restrict__ h,
                                                  float* __restrict__ out, int E) {
    int t = threadIdx.x;
    int e = blockIdx.x * 16 + (t >> 4);
    if (e >= E) return;
    int lane = t & 15;
    int s = ei[e];
    int d = ei[E + e];
    float norm = dinv[s] * dinv[d];
    float4 hv = *(const float4*)&h[(long)s * DIM + lane * 4];
    float* o = &out[(long)d * DIM + lane * 4];
    atomAddF(o + 0, hv.x * norm);
    atomAddF(o + 1, hv.y * norm);
    atomAddF(o + 2, hv.z * norm);
    atomAddF(o + 3, hv.w * norm);
}

extern "C" void kernel_launch(void* const* d_in, const int* in_sizes, int n_in,
                              void* d_out, int out_size, void* d_ws, size_t ws_size,
                              hipStream_t stream) {
    const float* x  = (const float*)d_in[0];
    const int*   ei = (const int*)d_in[1];   // [2,E] int32
    const float* W1 = (const float*)d_in[2];
    const float* b1 = (const float*)d_in[3];
    const float* W2 = (const float*)d_in[4];
    const float* b2 = (const float*)d_in[5];
    float* out = (float*)d_out;

    const int N = in_sizes[0] / DIM;   // 100000
    const int E = in_sizes[1] / 2;     // 1600000

    const int gn   = (N + 255) / 256;
    const int ge   = (E + 255) / 256;
    const int gagg = (N + 15) / 16;
    const int gmlp = (N + 63) / 64;
    const int gbk  = (E + BK_TILE - 1) / BK_TILE;

    // ws layout (256B-aligned bump). pairs aliases buf (pairs dead before MLP writes buf).
    size_t off = 0;
    auto bump = [&](size_t bytes) { size_t o = off; off = (off + bytes + 255) & ~(size_t)255; return o; };
    size_t o_dinv   = bump((size_t)N * 4);
    size_t o_rowptr = bump((size_t)(N + 1) * 4);
    size_t o_bcnt   = bump(NB * 4);
    size_t o_bbase  = bump((NB + 1) * 4);
    size_t o_gcur   = bump(NB * 4);
    size_t o_col    = bump((size_t)E * 4);
    size_t o_buf    = bump((size_t)N * DIM * 4);   // >= E*8 (25.6MB >= 12.8MB)
    size_t need_csr = off;

    char* ws = (char*)d_ws;

    if (ws_size >= need_csr) {
        float* dinv   = (float*)(ws + o_dinv);
        int*   rowptr = (int*)(ws + o_rowptr);
        int*   bcnt   = (int*)(ws + o_bcnt);
        int*   bbase  = (int*)(ws + o_bbase);
        int*   gcur   = (int*)(ws + o_gcur);
        int*   col    = (int*)(ws + o_col);
        float* buf    = (float*)(ws + o_buf);
        uint2* pairs  = (uint2*)(ws + o_buf);      // alias

        k_zero256<<<1, 256, 0, stream>>>(bcnt);
        k_hist256<<<gbk, 256, 0, stream>>>(ei, bcnt, E);
        k_scan_b<<<1, 256, 0, stream>>>(bcnt, bbase, gcur);
        k_bucket<<<gbk, 256, 0, stream>>>(ei, gcur, pairs, E);
        k_finish<<<NB, 256, 0, stream>>>(pairs, bbase, rowptr, dinv, col, N);

        // d_out = Ahat x
        k_agg_csr<false><<<gagg, 256, 0, stream>>>(rowptr, col, dinv, x, nullptr, out, N);
        // buf = relu(d_out @ W1 + b1) @ W2   (overwrites pairs -- dead)
        k_fused_mlp<<<gmlp, 256, 0, stream>>>(out, W1, b1, W2, buf, N);
        // d_out = Ahat buf + b2
        k_agg_csr<true><<<gagg, 256, 0, stream>>>(rowptr, col, dinv, buf, b2, out, N);
    } else {
        // -------- fallback (atomic scatter) --------
        float* dinv = (float*)ws;
        float* buf  = (float*)(ws + 512 * 1024);
        int gl = ((long)N * 16 + 255) / 256;
        int gedge = (E + 15) / 16;

        k_init_deg<<<gn, 256, 0, stream>>>(dinv, N);
        k_count_deg<<<ge, 256, 0, stream>>>(ei, dinv, E);
        k_rsqrt<<<gn, 256, 0, stream>>>(dinv, N);

        k_self<false><<<gl, 256, 0, stream>>>(x, dinv, nullptr, buf, N);
        k_edge_agg<<<gedge, 256, 0, stream>>>(ei, dinv, x, buf, E);
        k_fused_mlp<<<(N + 63) / 64, 256, 0, stream>>>(buf, W1, b1, W2, buf, N);
        k_self<true><<<gl, 256, 0, stream>>>(buf, dinv, b2, out, N);
        k_edge_agg<<<gedge, 256, 0, stream>>>(ei, dinv, buf, out, E);
    }
}